// Round 4
// baseline (1362.236 us; speedup 1.0000x reference)
//
#include <hip/hip_runtime.h>
#include <math.h>

#define HID 32
#define GRP 16
#define OUTC 10

struct P4 { const float* W[4]; const float* B[4]; float* C[4]; };

// ---------------------------------------------------------------------------
__global__ void fill_f32(float* p, float v, long long n) {
    long long i = (long long)blockIdx.x * blockDim.x + threadIdx.x;
    if (i < n) p[i] = v;
}
__global__ void fill_i32(int* p, int v, int n) {
    int i = blockIdx.x * blockDim.x + threadIdx.x;
    if (i < n) p[i] = v;
}

// ---------------------------------------------------------------------------
// CSR build (edge_index is layer-invariant: build once per call)
// ---------------------------------------------------------------------------
__global__ void count_deg(const int* __restrict__ dst, int* __restrict__ deg, int E) {
    int e = blockIdx.x * blockDim.x + threadIdx.x;
    if (e < E) atomicAdd(&deg[dst[e]], 1);
}

__global__ __launch_bounds__(256) void scan_offsets(const int* __restrict__ deg,
                                                    int* __restrict__ offs,
                                                    int* __restrict__ pos, int n) {
    __shared__ int partial[256];
    const int t = threadIdx.x;
    const int chunk = (n + 255) / 256;
    const int start = t * chunk;
    const int end   = min(start + chunk, n);
    int sum = 0;
    for (int i = start; i < end; i++) sum += deg[i];
    partial[t] = sum;
    __syncthreads();
    for (int s = 1; s < 256; s <<= 1) {
        int v = (t >= s) ? partial[t - s] : 0;
        __syncthreads();
        partial[t] += v;
        __syncthreads();
    }
    int base = (t == 0) ? 0 : partial[t - 1];
    for (int i = start; i < end; i++) {
        offs[i] = base; pos[i] = base;
        base += deg[i];
    }
    if (t == 255) offs[n] = base;
}

__global__ void scatter_edges(const int* __restrict__ dst, int* __restrict__ pos,
                              int* __restrict__ perm, int E) {
    int e = blockIdx.x * blockDim.x + threadIdx.x;
    if (e < E) {
        int slot = atomicAdd(&pos[dst[e]], 1);
        perm[slot] = e;
    }
}

__global__ void gather_src(const int* __restrict__ perm, const int* __restrict__ src,
                           int* __restrict__ srcPerm, int E) {
    int i = blockIdx.x * blockDim.x + threadIdx.x;
    if (i < E) srcPerm[i] = src[perm[i]];
}

// ---------------------------------------------------------------------------
// 4-way batched GEMM: C[z][M,N] = A[M,K] @ W[z][K,N] + B[z][N]
// BM=128 BN=128 BK=16, 8x8 per thread. K%16==0.
// ---------------------------------------------------------------------------
__global__ __launch_bounds__(256) void gemm4_128(
        const float* __restrict__ A, P4 p, int M, int K, int N) {
    __shared__ float As[16][132];
    __shared__ float Wsm[16][132];
    const float* __restrict__ W    = p.W[blockIdx.z];
    const float* __restrict__ bias = p.B[blockIdx.z];
    float*                    C    = p.C[blockIdx.z];
    const int tid = threadIdx.x;
    const int tx = tid & 15;
    const int ty = tid >> 4;
    const int bm = blockIdx.y * 128;
    const int bn = blockIdx.x * 128;

    float acc[8][8] = {};

    for (int k0 = 0; k0 < K; k0 += 16) {
        // A tile: 128 rows x 16 k — each thread 8 floats of one row half
        {
            int r  = tid >> 1;
            int kk = (tid & 1) * 8;
            float4 v0 = make_float4(0.f,0.f,0.f,0.f), v1 = v0;
            if (bm + r < M) {
                const float* ap = A + (size_t)(bm + r) * K + k0 + kk;
                v0 = *(const float4*)ap;
                v1 = *(const float4*)(ap + 4);
            }
            As[kk+0][r]=v0.x; As[kk+1][r]=v0.y; As[kk+2][r]=v0.z; As[kk+3][r]=v0.w;
            As[kk+4][r]=v1.x; As[kk+5][r]=v1.y; As[kk+6][r]=v1.z; As[kk+7][r]=v1.w;
        }
        // W tile: 16 k x 128 cols — each thread 2 float4
        #pragma unroll
        for (int h = 0; h < 2; h++) {
            int kk = (tid >> 5) + h * 8;
            int n4 = (tid & 31) * 4;
            float4 v4 = make_float4(0.f,0.f,0.f,0.f);
            if (bn + n4 < N)
                v4 = *(const float4*)(W + (size_t)(k0 + kk) * N + bn + n4);
            *(float4*)&Wsm[kk][n4] = v4;
        }
        __syncthreads();
        #pragma unroll
        for (int kk = 0; kk < 16; kk++) {
            float4 a0 = *(const float4*)&As[kk][ty * 4];
            float4 a1 = *(const float4*)&As[kk][64 + ty * 4];
            float4 b0 = *(const float4*)&Wsm[kk][tx * 4];
            float4 b1 = *(const float4*)&Wsm[kk][64 + tx * 4];
            float a[8] = {a0.x,a0.y,a0.z,a0.w,a1.x,a1.y,a1.z,a1.w};
            float b[8] = {b0.x,b0.y,b0.z,b0.w,b1.x,b1.y,b1.z,b1.w};
            #pragma unroll
            for (int i = 0; i < 8; i++)
                #pragma unroll
                for (int j = 0; j < 8; j++)
                    acc[i][j] += a[i] * b[j];
        }
        __syncthreads();
    }

    float bv[8];
    #pragma unroll
    for (int jh = 0; jh < 2; jh++)
        #pragma unroll
        for (int j = 0; j < 4; j++) {
            int n = bn + jh * 64 + tx * 4 + j;
            bv[jh*4+j] = (n < N) ? bias[n] : 0.f;
        }

    #pragma unroll
    for (int ih = 0; ih < 2; ih++)
        #pragma unroll
        for (int i = 0; i < 4; i++) {
            int m = bm + ih * 64 + ty * 4 + i;
            if (m >= M) continue;
            #pragma unroll
            for (int jh = 0; jh < 2; jh++) {
                int n0 = bn + jh * 64 + tx * 4;
                if (n0 + 3 < N) {
                    float4 o;
                    o.x = acc[ih*4+i][jh*4+0] + bv[jh*4+0];
                    o.y = acc[ih*4+i][jh*4+1] + bv[jh*4+1];
                    o.z = acc[ih*4+i][jh*4+2] + bv[jh*4+2];
                    o.w = acc[ih*4+i][jh*4+3] + bv[jh*4+3];
                    *(float4*)(C + (size_t)m * N + n0) = o;
                } else {
                    for (int j = 0; j < 4; j++) {
                        int n = n0 + j;
                        if (n < N) C[(size_t)m * N + n] = acc[ih*4+i][jh*4+j] + bv[jh*4+j];
                    }
                }
            }
        }
}

// ---------------------------------------------------------------------------
// 4-way batched small GEMM (layer 3, N=32): BM=64 BN=64 BK=16, 4x4/thread
// ---------------------------------------------------------------------------
__global__ __launch_bounds__(256) void gemm4_64(
        const float* __restrict__ A, P4 p, int M, int K, int N) {
    __shared__ float As[16][68];
    __shared__ float Wsm[16][68];
    const float* __restrict__ W    = p.W[blockIdx.z];
    const float* __restrict__ bias = p.B[blockIdx.z];
    float*                    C    = p.C[blockIdx.z];
    const int tid = threadIdx.x;
    const int tx = tid & 15;
    const int ty = tid >> 4;
    const int bm = blockIdx.y * 64;
    const int bn = blockIdx.x * 64;

    float acc[4][4] = {};

    for (int k0 = 0; k0 < K; k0 += 16) {
        {
            int r  = tid >> 2;          // 0..63
            int kk = (tid & 3) * 4;
            float4 v4 = make_float4(0.f,0.f,0.f,0.f);
            if (bm + r < M)
                v4 = *(const float4*)(A + (size_t)(bm + r) * K + k0 + kk);
            As[kk+0][r]=v4.x; As[kk+1][r]=v4.y; As[kk+2][r]=v4.z; As[kk+3][r]=v4.w;
        }
        {
            int kk = tid >> 4;
            int n4 = (tid & 15) * 4;
            float4 v4 = make_float4(0.f,0.f,0.f,0.f);
            if (bn + n4 < N)
                v4 = *(const float4*)(W + (size_t)(k0 + kk) * N + bn + n4);
            *(float4*)&Wsm[kk][n4] = v4;
        }
        __syncthreads();
        #pragma unroll
        for (int kk = 0; kk < 16; kk++) {
            float4 a0 = *(const float4*)&As[kk][ty * 4];
            float4 b0 = *(const float4*)&Wsm[kk][tx * 4];
            float a[4] = {a0.x,a0.y,a0.z,a0.w};
            float b[4] = {b0.x,b0.y,b0.z,b0.w};
            #pragma unroll
            for (int i = 0; i < 4; i++)
                #pragma unroll
                for (int j = 0; j < 4; j++)
                    acc[i][j] += a[i] * b[j];
        }
        __syncthreads();
    }

    #pragma unroll
    for (int i = 0; i < 4; i++) {
        int m = bm + ty * 4 + i;
        if (m >= M) continue;
        #pragma unroll
        for (int j = 0; j < 4; j++) {
            int n = bn + tx * 4 + j;
            if (n < N) C[(size_t)m * N + n] = acc[i][j] + bias[n];
        }
    }
}

// ---------------------------------------------------------------------------
// Fused per-node attention (online softmax over incoming edges) + skip + ReLU
// dof threads per node; 32 lanes per head. NOTE: sk may alias outb (each
// element read exactly once by the thread that writes it) -> no __restrict__.
// ---------------------------------------------------------------------------
__global__ __launch_bounds__(256) void attn_fused(
        const float* __restrict__ q, const float* __restrict__ k,
        const float* __restrict__ v, const float* sk,
        const int* __restrict__ offs, const int* __restrict__ srcPerm,
        float* outb, int N, int dof, float scale) {
    const int npb = blockDim.x / dof;
    const int sub = threadIdx.x / dof;
    const int j   = threadIdx.x % dof;
    const int n   = blockIdx.x * npb + sub;
    if (n >= N) return;

    const float qj = q[(size_t)n * dof + j];
    float m = -INFINITY, d = 0.f, acc = 0.f;

    const int i0 = offs[n], i1 = offs[n + 1];
    for (int i = i0; i < i1; ++i) {
        const int s = srcPerm[i];
        const float kj = k[(size_t)s * dof + j];
        const float vj = v[(size_t)s * dof + j];
        float prod = qj * kj;
        #pragma unroll
        for (int msk = 16; msk >= 1; msk >>= 1)
            prod += __shfl_xor(prod, msk, 32);
        const float sc = prod * scale;
        if (sc > m) {
            const float r = expf(m - sc);
            acc *= r; d *= r; m = sc;
        }
        const float p = expf(sc - m);
        acc += p * vj; d += p;
    }
    float val = acc / (d + 1e-16f) + sk[(size_t)n * dof + j];
    outb[(size_t)n * dof + j] = val > 0.f ? val : 0.f;
}

// ---------------------------------------------------------------------------
__global__ void pool_kernel(const float* __restrict__ h, const int* __restrict__ batch,
                            float* __restrict__ pooled, float* __restrict__ cnts, int N) {
    int t = blockIdx.x * blockDim.x + threadIdx.x;
    if (t >= N * HID) return;
    int n = t >> 5, j = t & 31;
    int g = batch[n];
    atomicAdd(&pooled[g * HID + j], h[t]);
    if (j == 0) atomicAdd(&cnts[g], 1.0f);
}

__global__ void head_kernel(const float* __restrict__ pooled, const float* __restrict__ cnts,
                            const float* __restrict__ wlin, const float* __restrict__ blin,
                            float* __restrict__ out) {
    int g = threadIdx.x;
    if (g >= GRP) return;
    float inv = 1.0f / fmaxf(cnts[g], 1.0f);
    float logit[OUTC];
    #pragma unroll
    for (int o = 0; o < OUTC; o++) logit[o] = blin[o];
    for (int j = 0; j < HID; j++) {
        float pv = pooled[g * HID + j] * inv;
        #pragma unroll
        for (int o = 0; o < OUTC; o++) logit[o] += pv * wlin[j * OUTC + o];
    }
    float mx = logit[0];
    #pragma unroll
    for (int o = 1; o < OUTC; o++) mx = fmaxf(mx, logit[o]);
    float sum = 0.f;
    #pragma unroll
    for (int o = 0; o < OUTC; o++) sum += expf(logit[o] - mx);
    float lse = mx + logf(sum);
    #pragma unroll
    for (int o = 0; o < OUTC; o++) out[g * OUTC + o] = logit[o] - lse;
}

// ---------------------------------------------------------------------------
extern "C" void kernel_launch(void* const* d_in, const int* in_sizes, int n_in,
                              void* d_out, int out_size, void* d_ws, size_t ws_size,
                              hipStream_t stream) {
    const float* x     = (const float*)d_in[0];
    const int*   ei    = (const int*)d_in[1];
    const int*   batch = (const int*)d_in[2];
    const int N = in_sizes[0] / 128;
    const int E = in_sizes[1] / 2;
    const int* src = ei;
    const int* dst = ei + E;

    // setup_inputs dict order per layer: wq, wk, wv, ws, bq, bk, bv, bs
    const float *W[4][4], *B[4][4];
    for (int i = 0; i < 4; i++)
        for (int j = 0; j < 4; j++) {
            W[i][j] = (const float*)d_in[3 + i * 8 + j];
            B[i][j] = (const float*)d_in[3 + i * 8 + 4 + j];
        }
    const float* wlin = (const float*)d_in[35];
    const float* blin = (const float*)d_in[36];

    // ---- workspace carving (bytes) ----
    char* base = (char*)d_ws;
    size_t off = 0;
    auto alloc = [&](size_t bytes) {
        char* p = base + off;
        off = (off + bytes + 255) & ~(size_t)255;
        return p;
    };
    float* qb   = (float*)alloc((size_t)N * 256 * 4);
    float* kb   = (float*)alloc((size_t)N * 256 * 4);
    float* vb   = (float*)alloc((size_t)N * 256 * 4);
    float* bufA = (float*)alloc((size_t)N * 256 * 4);
    float* bufB = (float*)alloc((size_t)N * 256 * 4);
    int*   deg  = (int*)alloc((size_t)N * 4);
    int*   pos  = (int*)alloc((size_t)N * 4);
    int*   offs = (int*)alloc((size_t)(N + 1) * 4);
    int*   perm = (int*)alloc((size_t)E * 4);
    int*   srcPerm = (int*)alloc((size_t)E * 4);
    float* pooled  = (float*)alloc(GRP * HID * 4);
    float* cnts    = (float*)alloc(GRP * 4);

    // ---- CSR build (once; edge_index constant across layers) ----
    fill_i32<<<(N + 255) / 256, 256, 0, stream>>>(deg, 0, N);
    count_deg<<<(E + 255) / 256, 256, 0, stream>>>(dst, deg, E);
    scan_offsets<<<1, 256, 0, stream>>>(deg, offs, pos, N);
    scatter_edges<<<(E + 255) / 256, 256, 0, stream>>>(dst, pos, perm, E);
    gather_src<<<(E + 255) / 256, 256, 0, stream>>>(perm, src, srcPerm, E);

    const int dims_in[4] = {128, 256, 256, 256};
    const int heads_l[4] = {8, 8, 8, 1};
    const float scale = 0.17677669529663687f; // 1/sqrt(32)

    const float* cur = x;
    float* skbufs[2] = {bufA, bufB};

    for (int L = 0; L < 4; L++) {
        const int di  = dims_in[L];
        const int H   = heads_l[L];
        const int dof = H * HID;
        float* skb = skbufs[L & 1];   // GEMM skip output; attn writes out in-place

        P4 p;
        for (int t = 0; t < 4; t++) { p.W[t] = W[L][t]; p.B[t] = B[L][t]; }
        p.C[0] = qb; p.C[1] = kb; p.C[2] = vb; p.C[3] = skb;

        if (dof >= 128) {
            dim3 gg((dof + 127) / 128, (N + 127) / 128, 4);
            gemm4_128<<<gg, 256, 0, stream>>>(cur, p, N, di, dof);
        } else {
            dim3 gg((dof + 63) / 64, (N + 63) / 64, 4);
            gemm4_64<<<gg, 256, 0, stream>>>(cur, p, N, di, dof);
        }

        const int npb = 256 / dof;
        attn_fused<<<(N + npb - 1) / npb, 256, 0, stream>>>(
            qb, kb, vb, skb, offs, srcPerm, skb, N, dof, scale);

        cur = skb;
    }

    fill_f32<<<(GRP * HID + 255) / 256, 256, 0, stream>>>(pooled, 0.f, GRP * HID);
    fill_f32<<<1, 256, 0, stream>>>(cnts, 0.f, GRP);
    pool_kernel<<<(N * HID + 255) / 256, 256, 0, stream>>>(cur, batch, pooled, cnts, N);
    head_kernel<<<1, 64, 0, stream>>>(pooled, cnts, wlin, blin, (float*)d_out);
}

// Round 6
// 950.849 us; speedup vs baseline: 1.4327x; 1.4327x over previous
//
#include <hip/hip_runtime.h>
#include <math.h>

#define HID 32
#define GRP 16
#define OUTC 10

typedef __attribute__((ext_vector_type(8))) short short8;
typedef __attribute__((ext_vector_type(4))) float f32x4;

struct P4     { const float*  W[4]; const float* B[4]; float* C[4]; };
struct W4     { const float*  w[4]; };
struct PZmfma { const ushort* wh[4]; const ushort* wl[4]; const float* bias[4]; float* C[4]; };

// ---------------------------------------------------------------------------
__device__ __forceinline__ ushort f2bf(float f) {
    unsigned u = __float_as_uint(f);
    unsigned r = (u + 0x7FFFu + ((u >> 16) & 1u)) >> 16;   // RNE
    return (ushort)r;
}
__device__ __forceinline__ float bf2f(ushort h) {
    return __uint_as_float(((unsigned)h) << 16);
}

// ---------------------------------------------------------------------------
__global__ void fill_i32(int* p, int v, int n) {
    int i = blockIdx.x * blockDim.x + threadIdx.x;
    if (i < n) p[i] = v;
}

// ---------------------------------------------------------------------------
// CSR build (edge_index is layer-invariant: build once per call)
// ---------------------------------------------------------------------------
__global__ void count_deg(const int* __restrict__ dst, int* __restrict__ deg, int E) {
    int e = blockIdx.x * blockDim.x + threadIdx.x;
    if (e < E) atomicAdd(&deg[dst[e]], 1);
}

__global__ __launch_bounds__(256) void scan_offsets(const int* __restrict__ deg,
                                                    int* __restrict__ offs,
                                                    int* __restrict__ pos, int n) {
    __shared__ int partial[256];
    const int t = threadIdx.x;
    const int chunk = (n + 255) / 256;
    const int start = t * chunk;
    const int end   = min(start + chunk, n);
    int sum = 0;
    for (int i = start; i < end; i++) sum += deg[i];
    partial[t] = sum;
    __syncthreads();
    for (int s = 1; s < 256; s <<= 1) {
        int v = (t >= s) ? partial[t - s] : 0;
        __syncthreads();
        partial[t] += v;
        __syncthreads();
    }
    int base = (t == 0) ? 0 : partial[t - 1];
    for (int i = start; i < end; i++) {
        offs[i] = base; pos[i] = base;
        base += deg[i];
    }
    if (t == 255) offs[n] = base;
}

__global__ void scatter_edges(const int* __restrict__ dst, int* __restrict__ pos,
                              int* __restrict__ perm, int E) {
    int e = blockIdx.x * blockDim.x + threadIdx.x;
    if (e < E) {
        int slot = atomicAdd(&pos[dst[e]], 1);
        perm[slot] = e;
    }
}

__global__ void gather_src(const int* __restrict__ perm, const int* __restrict__ src,
                           int* __restrict__ srcPerm, int E) {
    int i = blockIdx.x * blockDim.x + threadIdx.x;
    if (i < E) srcPerm[i] = src[perm[i]];
}

// ---------------------------------------------------------------------------
// fp32 -> bf16 hi/lo split (elementwise, keeps [M][K] layout)
// ---------------------------------------------------------------------------
__global__ void split_f32(const float* __restrict__ x, ushort* __restrict__ hi,
                          ushort* __restrict__ lo, long long n) {
    long long i = (long long)blockIdx.x * blockDim.x + threadIdx.x;
    if (i >= n) return;
    float v = x[i];
    ushort h = f2bf(v);
    ushort l = f2bf(v - bf2f(h));
    hi[i] = h; lo[i] = l;
}

// W [K][N=256] fp32 -> Wt hi/lo [z][n][k] bf16 (transposed for MFMA B-frag)
__global__ void splitT_w(W4 wp, ushort* __restrict__ wh, ushort* __restrict__ wl, int K) {
    const int NN = 256;
    int z = blockIdx.y;
    const float* W = wp.w[z];
    ushort* whz = wh + (size_t)z * K * NN;
    ushort* wlz = wl + (size_t)z * K * NN;
    int i = blockIdx.x * blockDim.x + threadIdx.x;
    if (i >= K * NN) return;
    int k = i / NN, n = i - k * NN;
    float v = W[i];
    ushort h = f2bf(v);
    ushort l = f2bf(v - bf2f(h));
    whz[(size_t)n * K + k] = h;
    wlz[(size_t)n * K + k] = l;
}

// ---------------------------------------------------------------------------
// MFMA bf16-split GEMM: C[z][M,256] = A[M,K] @ W[z][K,256] + bias[z]
// BM=128 BN=128, 4 waves (2x2), each wave 64x64 = 4x4 frags of 16x16x32.
// A/W pre-split into bf16 hi/lo. 3-product split: hh + hl + lh.
// LDS: 4 x [128][32] bf16 tiles, XOR-swizzled (byte ^= (row&7)<<4).
// ---------------------------------------------------------------------------
#define AHI_OFF 0
#define ALO_OFF 8192
#define BHI_OFF 16384
#define BLO_OFF 24576

__global__ __launch_bounds__(256) void gemm4_mfma(
        const ushort* __restrict__ Ah, const ushort* __restrict__ Al,
        PZmfma p, int M, int K) {
    __shared__ __align__(16) unsigned char smem[32768];
    const int NN = 256;
    const int t  = threadIdx.x;
    const int bn = blockIdx.x * 128;
    const int bm = blockIdx.y * 128;
    const int z  = blockIdx.z;
    const ushort* Wh = p.wh[z];
    const ushort* Wl = p.wl[z];

    const int wid  = t >> 6;
    const int lane = t & 63;
    const int wr = wid >> 1, wc = wid & 1;
    const int l15 = lane & 15, g = lane >> 4;

    f32x4 acc[4][4];
    const f32x4 zero4 = {0.f, 0.f, 0.f, 0.f};
    #pragma unroll
    for (int m = 0; m < 4; m++)
        #pragma unroll
        for (int n = 0; n < 4; n++) acc[m][n] = zero4;

    // staging coords: thread t stages row (t>>1), 32B half (t&1) of each tile
    const int srow = t >> 1;
    const int sseg = t & 1;
    const int o0 = sseg * 2;           // first 16B slot index (of 4 per row)
    // swizzled LDS byte addresses (each slot XORed independently!)
    const int swz = (srow & 7) << 4;
    const int la0 = (srow * 64 + o0 * 16) ^ swz;
    const int la1 = (srow * 64 + (o0 + 1) * 16) ^ swz;
    const bool arow_ok = (bm + srow) < M;
    const size_t abase = (size_t)(bm + srow) * K + sseg * 16;
    const size_t bbase = (size_t)(bn + srow) * K + sseg * 16;

    for (int k0 = 0; k0 < K; k0 += 32) {
        uint4 vah0 = make_uint4(0,0,0,0), vah1 = vah0, val0 = vah0, val1 = vah0;
        if (arow_ok) {
            vah0 = *(const uint4*)(Ah + abase + k0);
            vah1 = *(const uint4*)(Ah + abase + k0 + 8);
            val0 = *(const uint4*)(Al + abase + k0);
            val1 = *(const uint4*)(Al + abase + k0 + 8);
        }
        uint4 vbh0 = *(const uint4*)(Wh + bbase + k0);
        uint4 vbh1 = *(const uint4*)(Wh + bbase + k0 + 8);
        uint4 vbl0 = *(const uint4*)(Wl + bbase + k0);
        uint4 vbl1 = *(const uint4*)(Wl + bbase + k0 + 8);
        __syncthreads();
        *(uint4*)(smem + AHI_OFF + la0) = vah0;
        *(uint4*)(smem + AHI_OFF + la1) = vah1;
        *(uint4*)(smem + ALO_OFF + la0) = val0;
        *(uint4*)(smem + ALO_OFF + la1) = val1;
        *(uint4*)(smem + BHI_OFF + la0) = vbh0;
        *(uint4*)(smem + BHI_OFF + la1) = vbh1;
        *(uint4*)(smem + BLO_OFF + la0) = vbl0;
        *(uint4*)(smem + BLO_OFF + la1) = vbl1;
        __syncthreads();

        // B fragments (cols wc*64 + n*16 + l15, k-octet g)
        short8 bh[4], bl[4];
        #pragma unroll
        for (int n = 0; n < 4; n++) {
            int r  = wc * 64 + n * 16 + l15;
            int ba = (r * 64 + g * 16) ^ ((r & 7) << 4);
            bh[n] = *(const short8*)(smem + BHI_OFF + ba);
            bl[n] = *(const short8*)(smem + BLO_OFF + ba);
        }
        #pragma unroll
        for (int m = 0; m < 4; m++) {
            int r  = wr * 64 + m * 16 + l15;
            int aa = (r * 64 + g * 16) ^ ((r & 7) << 4);
            short8 ah = *(const short8*)(smem + AHI_OFF + aa);
            short8 al = *(const short8*)(smem + ALO_OFF + aa);
            #pragma unroll
            for (int n = 0; n < 4; n++) {
                acc[m][n] = __builtin_amdgcn_mfma_f32_16x16x32_bf16(ah, bh[n], acc[m][n], 0, 0, 0);
                acc[m][n] = __builtin_amdgcn_mfma_f32_16x16x32_bf16(ah, bl[n], acc[m][n], 0, 0, 0);
                acc[m][n] = __builtin_amdgcn_mfma_f32_16x16x32_bf16(al, bh[n], acc[m][n], 0, 0, 0);
            }
        }
    }

    // epilogue: C[row][col], row = bm+wr*64+m*16+g*4+i, col = bn+wc*64+n*16+l15
    float* C = p.C[z];
    const float* bias = p.bias[z];
    float bv[4];
    #pragma unroll
    for (int n = 0; n < 4; n++) bv[n] = bias[bn + wc * 64 + n * 16 + l15];
    #pragma unroll
    for (int m = 0; m < 4; m++) {
        int crow = bm + wr * 64 + m * 16 + g * 4;
        #pragma unroll
        for (int n = 0; n < 4; n++) {
            int ccol = bn + wc * 64 + n * 16 + l15;
            #pragma unroll
            for (int i = 0; i < 4; i++) {
                if (crow + i < M)
                    C[(size_t)(crow + i) * NN + ccol] = acc[m][n][i] + bv[n];
            }
        }
    }
}

// ---------------------------------------------------------------------------
// 4-way batched small GEMM (layer 3, N=32): BM=64 BN=64 BK=16, 4x4/thread
// ---------------------------------------------------------------------------
__global__ __launch_bounds__(256) void gemm4_64(
        const float* __restrict__ A, P4 p, int M, int K, int N) {
    __shared__ float As[16][68];
    __shared__ float Wsm[16][68];
    const float* __restrict__ W    = p.W[blockIdx.z];
    const float* __restrict__ bias = p.B[blockIdx.z];
    float*                    C    = p.C[blockIdx.z];
    const int tid = threadIdx.x;
    const int tx = tid & 15;
    const int ty = tid >> 4;
    const int bm = blockIdx.y * 64;
    const int bn = blockIdx.x * 64;

    float acc[4][4] = {};

    for (int k0 = 0; k0 < K; k0 += 16) {
        {
            int r  = tid >> 2;
            int kk = (tid & 3) * 4;
            float4 v4 = make_float4(0.f,0.f,0.f,0.f);
            if (bm + r < M)
                v4 = *(const float4*)(A + (size_t)(bm + r) * K + k0 + kk);
            As[kk+0][r]=v4.x; As[kk+1][r]=v4.y; As[kk+2][r]=v4.z; As[kk+3][r]=v4.w;
        }
        {
            int kk = tid >> 4;
            int n4 = (tid & 15) * 4;
            float4 v4 = make_float4(0.f,0.f,0.f,0.f);
            if (bn + n4 < N)
                v4 = *(const float4*)(W + (size_t)(k0 + kk) * N + bn + n4);
            *(float4*)&Wsm[kk][n4] = v4;
        }
        __syncthreads();
        #pragma unroll
        for (int kk = 0; kk < 16; kk++) {
            float4 a0 = *(const float4*)&As[kk][ty * 4];
            float4 b0 = *(const float4*)&Wsm[kk][tx * 4];
            float a[4] = {a0.x,a0.y,a0.z,a0.w};
            float b[4] = {b0.x,b0.y,b0.z,b0.w};
            #pragma unroll
            for (int i = 0; i < 4; i++)
                #pragma unroll
                for (int j = 0; j < 4; j++)
                    acc[i][j] += a[i] * b[j];
        }
        __syncthreads();
    }

    #pragma unroll
    for (int i = 0; i < 4; i++) {
        int m = bm + ty * 4 + i;
        if (m >= M) continue;
        #pragma unroll
        for (int j = 0; j < 4; j++) {
            int n = bn + tx * 4 + j;
            if (n < N) C[(size_t)m * N + n] = acc[i][j] + bias[n];
        }
    }
}

// ---------------------------------------------------------------------------
// Fused per-node attention (online softmax over incoming edges) + skip + ReLU
// dof threads per node; 32 lanes per head. sk may alias outb.
// ---------------------------------------------------------------------------
__global__ __launch_bounds__(256) void attn_fused(
        const float* __restrict__ q, const float* __restrict__ k,
        const float* __restrict__ v, const float* sk,
        const int* __restrict__ offs, const int* __restrict__ srcPerm,
        float* outb, int N, int dof, float scale) {
    const int npb = blockDim.x / dof;
    const int sub = threadIdx.x / dof;
    const int j   = threadIdx.x % dof;
    const int n   = blockIdx.x * npb + sub;
    if (n >= N) return;

    const float qj = q[(size_t)n * dof + j];
    float m = -INFINITY, d = 0.f, acc = 0.f;

    const int i0 = offs[n], i1 = offs[n + 1];
    for (int i = i0; i < i1; ++i) {
        const int s = srcPerm[i];
        const float kj = k[(size_t)s * dof + j];
        const float vj = v[(size_t)s * dof + j];
        float prod = qj * kj;
        #pragma unroll
        for (int msk = 16; msk >= 1; msk >>= 1)
            prod += __shfl_xor(prod, msk, 32);
        const float sc = prod * scale;
        if (sc > m) {
            const float r = expf(m - sc);
            acc *= r; d *= r; m = sc;
        }
        const float p = expf(sc - m);
        acc += p * vj; d += p;
    }
    float val = acc / (d + 1e-16f) + sk[(size_t)n * dof + j];
    outb[(size_t)n * dof + j] = val > 0.f ? val : 0.f;
}

// ---------------------------------------------------------------------------
// graph boundaries from sorted batch -> gofs[0..G]
// ---------------------------------------------------------------------------
__global__ void graph_offsets(const int* __restrict__ batch, int* __restrict__ gofs,
                              int N, int G) {
    int n = blockIdx.x * blockDim.x + threadIdx.x;
    if (n >= N) return;
    int b = batch[n];
    if (n == 0) { for (int g = 0; g <= b; g++) gofs[g] = 0; }
    else {
        int pb = batch[n - 1];
        if (pb != b) for (int g = pb + 1; g <= b; g++) gofs[g] = n;
    }
    if (n == N - 1) { for (int g = b + 1; g <= G; g++) gofs[g] = N; }
}

// segmented mean-pool: one block per graph, no atomics; writes the MEAN
__global__ __launch_bounds__(1024) void pool_seg(const float* __restrict__ h,
                                                 const int* __restrict__ gofs,
                                                 float* __restrict__ pooled) {
    const int g = blockIdx.x;
    const int j = threadIdx.x & 31;
    const int r = threadIdx.x >> 5;        // 0..31
    const int s0 = gofs[g], s1 = gofs[g + 1];
    float s = 0.f;
    for (int n = s0 + r; n < s1; n += 32) s += h[(size_t)n * HID + j];
    __shared__ float red[32][33];
    red[r][j] = s;
    __syncthreads();
    if (r == 0) {
        float tt = 0.f;
        #pragma unroll
        for (int i = 0; i < 32; i++) tt += red[i][j];
        pooled[g * HID + j] = tt / fmaxf((float)(s1 - s0), 1.f);
    }
}

// logits = pooled_mean @ wlin + blin ; log_softmax
__global__ void head_kernel(const float* __restrict__ pooled,
                            const float* __restrict__ wlin, const float* __restrict__ blin,
                            float* __restrict__ out) {
    int g = threadIdx.x;
    if (g >= GRP) return;
    float logit[OUTC];
    #pragma unroll
    for (int o = 0; o < OUTC; o++) logit[o] = blin[o];
    for (int j = 0; j < HID; j++) {
        float pv = pooled[g * HID + j];
        #pragma unroll
        for (int o = 0; o < OUTC; o++) logit[o] += pv * wlin[j * OUTC + o];
    }
    float mx = logit[0];
    #pragma unroll
    for (int o = 1; o < OUTC; o++) mx = fmaxf(mx, logit[o]);
    float sum = 0.f;
    #pragma unroll
    for (int o = 0; o < OUTC; o++) sum += expf(logit[o] - mx);
    float lse = mx + logf(sum);
    #pragma unroll
    for (int o = 0; o < OUTC; o++) out[g * OUTC + o] = logit[o] - lse;
}

// ---------------------------------------------------------------------------
extern "C" void kernel_launch(void* const* d_in, const int* in_sizes, int n_in,
                              void* d_out, int out_size, void* d_ws, size_t ws_size,
                              hipStream_t stream) {
    const float* x     = (const float*)d_in[0];
    const int*   ei    = (const int*)d_in[1];
    const int*   batch = (const int*)d_in[2];
    const int N = in_sizes[0] / 128;
    const int E = in_sizes[1] / 2;
    const int* src = ei;
    const int* dst = ei + E;

    // setup_inputs dict order per layer: wq, wk, wv, ws, bq, bk, bv, bs
    const float *W[4][4], *B[4][4];
    for (int i = 0; i < 4; i++)
        for (int j = 0; j < 4; j++) {
            W[i][j] = (const float*)d_in[3 + i * 8 + j];
            B[i][j] = (const float*)d_in[3 + i * 8 + 4 + j];
        }
    const float* wlin = (const float*)d_in[35];
    const float* blin = (const float*)d_in[36];

    // ---- workspace carving (bytes) ----
    char* base = (char*)d_ws;
    size_t off = 0;
    auto alloc = [&](size_t bytes) {
        char* p = base + off;
        off = (off + bytes + 255) & ~(size_t)255;
        return p;
    };
    float*  qb   = (float*)alloc((size_t)N * 256 * 4);
    float*  kb   = (float*)alloc((size_t)N * 256 * 4);
    float*  vb   = (float*)alloc((size_t)N * 256 * 4);
    float*  bufA = (float*)alloc((size_t)N * 256 * 4);
    float*  bufB = (float*)alloc((size_t)N * 256 * 4);
    ushort* ahi  = (ushort*)alloc((size_t)N * 256 * 2);
    ushort* alo  = (ushort*)alloc((size_t)N * 256 * 2);
    // Wt splits: L0: 4*256*128 ; L1,L2: 4*256*256 each
    ushort* wth[3], *wtl[3];
    const int Ks[3] = {128, 256, 256};
    for (int L = 0; L < 3; L++) {
        wth[L] = (ushort*)alloc((size_t)4 * 256 * Ks[L] * 2);
        wtl[L] = (ushort*)alloc((size_t)4 * 256 * Ks[L] * 2);
    }
    int*   deg     = (int*)alloc((size_t)N * 4);
    int*   pos     = (int*)alloc((size_t)N * 4);
    int*   offs    = (int*)alloc((size_t)(N + 1) * 4);
    int*   perm    = (int*)alloc((size_t)E * 4);
    int*   srcPerm = (int*)alloc((size_t)E * 4);
    int*   gofs    = (int*)alloc((GRP + 1) * 4);
    float* pooled  = (float*)alloc(GRP * HID * 4);

    // ---- CSR build (once; edge_index constant across layers) ----
    fill_i32<<<(N + 255) / 256, 256, 0, stream>>>(deg, 0, N);
    count_deg<<<(E + 255) / 256, 256, 0, stream>>>(dst, deg, E);
    scan_offsets<<<1, 256, 0, stream>>>(deg, offs, pos, N);
    scatter_edges<<<(E + 255) / 256, 256, 0, stream>>>(dst, pos, perm, E);
    gather_src<<<(E + 255) / 256, 256, 0, stream>>>(perm, src, srcPerm, E);

    // ---- W hi/lo split + transpose (layers 0..2, all z), once ----
    for (int L = 0; L < 3; L++) {
        W4 wp;
        for (int z = 0; z < 4; z++) wp.w[z] = W[L][z];
        dim3 gw((Ks[L] * 256 + 255) / 256, 4);
        splitT_w<<<gw, 256, 0, stream>>>(wp, wth[L], wtl[L], Ks[L]);
    }

    const int heads_l[4] = {8, 8, 8, 1};
    const float scale = 0.17677669529663687f; // 1/sqrt(32)

    const float* cur = x;
    float* skbufs[2] = {bufA, bufB};

    for (int L = 0; L < 4; L++) {
        const int H   = heads_l[L];
        const int dof = H * HID;
        float* skb = skbufs[L & 1];

        if (L < 3) {
            const int K = Ks[L];
            long long nel = (long long)N * K;
            split_f32<<<(int)((nel + 255) / 256), 256, 0, stream>>>(cur, ahi, alo, nel);

            PZmfma p;
            for (int z = 0; z < 4; z++) {
                p.wh[z] = wth[L] + (size_t)z * 256 * K;
                p.wl[z] = wtl[L] + (size_t)z * 256 * K;
                p.bias[z] = B[L][z];
            }
            p.C[0] = qb; p.C[1] = kb; p.C[2] = vb; p.C[3] = skb;
            dim3 gg(2, (N + 127) / 128, 4);
            gemm4_mfma<<<gg, 256, 0, stream>>>(ahi, alo, p, N, K);
        } else {
            P4 p;
            for (int t = 0; t < 4; t++) { p.W[t] = W[L][t]; p.B[t] = B[L][t]; }
            p.C[0] = qb; p.C[1] = kb; p.C[2] = vb; p.C[3] = skb;
            dim3 gg(1, (N + 63) / 64, 4);
            gemm4_64<<<gg, 256, 0, stream>>>(cur, p, N, 256, 32);
        }

        const int npb = 256 / dof;
        attn_fused<<<(N + npb - 1) / npb, 256, 0, stream>>>(
            qb, kb, vb, skb, offs, srcPerm, skb, N, dof, scale);

        cur = skb;
    }

    graph_offsets<<<(N + 255) / 256, 256, 0, stream>>>(batch, gofs, N, GRP);
    pool_seg<<<GRP, 1024, 0, stream>>>(cur, gofs, pooled);
    head_kernel<<<1, 64, 0, stream>>>(pooled, wlin, blin, (float*)d_out);
}

// Round 8
// 727.806 us; speedup vs baseline: 1.8717x; 1.3065x over previous
//
#include <hip/hip_runtime.h>
#include <math.h>

#define HID 32
#define GRP 16
#define OUTC 10

typedef __attribute__((ext_vector_type(8))) short short8;
typedef __attribute__((ext_vector_type(4))) float f32x4;

struct P4     { const float*  W[4]; const float* B[4]; float* C[4]; };
struct W4     { const float*  w[4]; };
struct PZmfma { const ushort* wh[4]; const ushort* wl[4]; const float* bias[4]; float* C[4]; };

// ---------------------------------------------------------------------------
__device__ __forceinline__ ushort f2bf(float f) {
    unsigned u = __float_as_uint(f);
    unsigned r = (u + 0x7FFFu + ((u >> 16) & 1u)) >> 16;   // RNE
    return (ushort)r;
}
__device__ __forceinline__ float bf2f(ushort h) {
    return __uint_as_float(((unsigned)h) << 16);
}

// ---------------------------------------------------------------------------
__global__ void fill_i32(int* p, int v, int n) {
    int i = blockIdx.x * blockDim.x + threadIdx.x;
    if (i < n) p[i] = v;
}

// ---------------------------------------------------------------------------
// CSR build (edge_index is layer-invariant: build once per call)
// ---------------------------------------------------------------------------
__global__ void count_deg(const int* __restrict__ dst, int* __restrict__ deg, int E) {
    int e = blockIdx.x * blockDim.x + threadIdx.x;
    if (e < E) atomicAdd(&deg[dst[e]], 1);
}

__global__ __launch_bounds__(256) void scan_offsets(const int* __restrict__ deg,
                                                    int* __restrict__ offs,
                                                    int* __restrict__ pos, int n) {
    __shared__ int partial[256];
    const int t = threadIdx.x;
    const int chunk = (n + 255) / 256;
    const int start = t * chunk;
    const int end   = min(start + chunk, n);
    int sum = 0;
    for (int i = start; i < end; i++) sum += deg[i];
    partial[t] = sum;
    __syncthreads();
    for (int s = 1; s < 256; s <<= 1) {
        int v = (t >= s) ? partial[t - s] : 0;
        __syncthreads();
        partial[t] += v;
        __syncthreads();
    }
    int base = (t == 0) ? 0 : partial[t - 1];
    for (int i = start; i < end; i++) {
        offs[i] = base; pos[i] = base;
        base += deg[i];
    }
    if (t == 255) offs[n] = base;
}

__global__ void scatter_edges(const int* __restrict__ dst, int* __restrict__ pos,
                              int* __restrict__ perm, int E) {
    int e = blockIdx.x * blockDim.x + threadIdx.x;
    if (e < E) {
        int slot = atomicAdd(&pos[dst[e]], 1);
        perm[slot] = e;
    }
}

__global__ void gather_src(const int* __restrict__ perm, const int* __restrict__ src,
                           int* __restrict__ srcPerm, int E) {
    int i = blockIdx.x * blockDim.x + threadIdx.x;
    if (i < E) srcPerm[i] = src[perm[i]];
}

// ---------------------------------------------------------------------------
// fp32 -> bf16 hi/lo split (elementwise, keeps [M][K] layout)
// ---------------------------------------------------------------------------
__global__ void split_f32(const float* __restrict__ x, ushort* __restrict__ hi,
                          ushort* __restrict__ lo, long long n) {
    long long i = (long long)blockIdx.x * blockDim.x + threadIdx.x;
    if (i >= n) return;
    float v = x[i];
    ushort h = f2bf(v);
    ushort l = f2bf(v - bf2f(h));
    hi[i] = h; lo[i] = l;
}

// W [K][N=256] fp32 -> Wt hi/lo [z][n][k] bf16 (transposed for MFMA B-frag)
__global__ void splitT_w(W4 wp, ushort* __restrict__ wh, ushort* __restrict__ wl, int K) {
    const int NN = 256;
    int z = blockIdx.y;
    const float* W = wp.w[z];
    ushort* whz = wh + (size_t)z * K * NN;
    ushort* wlz = wl + (size_t)z * K * NN;
    int i = blockIdx.x * blockDim.x + threadIdx.x;
    if (i >= K * NN) return;
    int k = i / NN, n = i - k * NN;
    float v = W[i];
    ushort h = f2bf(v);
    ushort l = f2bf(v - bf2f(h));
    whz[(size_t)n * K + k] = h;
    wlz[(size_t)n * K + k] = l;
}

// ---------------------------------------------------------------------------
// MFMA bf16-split GEMM: C[z][M,256] = A[M,K] @ W[z][K,256] + bias[z]
// BM=128 BN=128, 4 waves (2x2), each wave 64x64 = 4x4 frags of 16x16x32.
// A/W pre-split into bf16 hi/lo. 3-product split: hh + hl + lh.
// LDS: 4 x [128][32] bf16 tiles, XOR-swizzled (byte ^= (row&7)<<4).
// ---------------------------------------------------------------------------
#define AHI_OFF 0
#define ALO_OFF 8192
#define BHI_OFF 16384
#define BLO_OFF 24576

__global__ __launch_bounds__(256) void gemm4_mfma(
        const ushort* __restrict__ Ah, const ushort* __restrict__ Al,
        PZmfma p, int M, int K) {
    __shared__ __align__(16) unsigned char smem[32768];
    const int NN = 256;
    const int t  = threadIdx.x;
    const int bn = blockIdx.x * 128;
    const int bm = blockIdx.y * 128;
    const int z  = blockIdx.z;
    const ushort* Wh = p.wh[z];
    const ushort* Wl = p.wl[z];

    const int wid  = t >> 6;
    const int lane = t & 63;
    const int wr = wid >> 1, wc = wid & 1;
    const int l15 = lane & 15, g = lane >> 4;

    f32x4 acc[4][4];
    const f32x4 zero4 = {0.f, 0.f, 0.f, 0.f};
    #pragma unroll
    for (int m = 0; m < 4; m++)
        #pragma unroll
        for (int n = 0; n < 4; n++) acc[m][n] = zero4;

    // staging coords: thread t stages row (t>>1), 32B half (t&1) of each tile
    const int srow = t >> 1;
    const int sseg = t & 1;
    const int o0 = sseg * 2;           // first 16B slot index (of 4 per row)
    // swizzled LDS byte addresses (each slot XORed independently!)
    const int swz = (srow & 7) << 4;
    const int la0 = (srow * 64 + o0 * 16) ^ swz;
    const int la1 = (srow * 64 + (o0 + 1) * 16) ^ swz;
    const bool arow_ok = (bm + srow) < M;
    const size_t abase = (size_t)(bm + srow) * K + sseg * 16;
    const size_t bbase = (size_t)(bn + srow) * K + sseg * 16;

    for (int k0 = 0; k0 < K; k0 += 32) {
        uint4 vah0 = make_uint4(0,0,0,0), vah1 = vah0, val0 = vah0, val1 = vah0;
        if (arow_ok) {
            vah0 = *(const uint4*)(Ah + abase + k0);
            vah1 = *(const uint4*)(Ah + abase + k0 + 8);
            val0 = *(const uint4*)(Al + abase + k0);
            val1 = *(const uint4*)(Al + abase + k0 + 8);
        }
        uint4 vbh0 = *(const uint4*)(Wh + bbase + k0);
        uint4 vbh1 = *(const uint4*)(Wh + bbase + k0 + 8);
        uint4 vbl0 = *(const uint4*)(Wl + bbase + k0);
        uint4 vbl1 = *(const uint4*)(Wl + bbase + k0 + 8);
        __syncthreads();
        *(uint4*)(smem + AHI_OFF + la0) = vah0;
        *(uint4*)(smem + AHI_OFF + la1) = vah1;
        *(uint4*)(smem + ALO_OFF + la0) = val0;
        *(uint4*)(smem + ALO_OFF + la1) = val1;
        *(uint4*)(smem + BHI_OFF + la0) = vbh0;
        *(uint4*)(smem + BHI_OFF + la1) = vbh1;
        *(uint4*)(smem + BLO_OFF + la0) = vbl0;
        *(uint4*)(smem + BLO_OFF + la1) = vbl1;
        __syncthreads();

        // B fragments (cols wc*64 + n*16 + l15, k-octet g)
        short8 bh[4], bl[4];
        #pragma unroll
        for (int n = 0; n < 4; n++) {
            int r  = wc * 64 + n * 16 + l15;
            int ba = (r * 64 + g * 16) ^ ((r & 7) << 4);
            bh[n] = *(const short8*)(smem + BHI_OFF + ba);
            bl[n] = *(const short8*)(smem + BLO_OFF + ba);
        }
        #pragma unroll
        for (int m = 0; m < 4; m++) {
            int r  = wr * 64 + m * 16 + l15;
            int aa = (r * 64 + g * 16) ^ ((r & 7) << 4);
            short8 ah = *(const short8*)(smem + AHI_OFF + aa);
            short8 al = *(const short8*)(smem + ALO_OFF + aa);
            #pragma unroll
            for (int n = 0; n < 4; n++) {
                acc[m][n] = __builtin_amdgcn_mfma_f32_16x16x32_bf16(ah, bh[n], acc[m][n], 0, 0, 0);
                acc[m][n] = __builtin_amdgcn_mfma_f32_16x16x32_bf16(ah, bl[n], acc[m][n], 0, 0, 0);
                acc[m][n] = __builtin_amdgcn_mfma_f32_16x16x32_bf16(al, bh[n], acc[m][n], 0, 0, 0);
            }
        }
    }

    // epilogue: C[row][col], row = bm+wr*64+m*16+g*4+i, col = bn+wc*64+n*16+l15
    float* C = p.C[z];
    const float* bias = p.bias[z];
    float bv[4];
    #pragma unroll
    for (int n = 0; n < 4; n++) bv[n] = bias[bn + wc * 64 + n * 16 + l15];
    #pragma unroll
    for (int m = 0; m < 4; m++) {
        int crow = bm + wr * 64 + m * 16 + g * 4;
        #pragma unroll
        for (int n = 0; n < 4; n++) {
            int ccol = bn + wc * 64 + n * 16 + l15;
            #pragma unroll
            for (int i = 0; i < 4; i++) {
                if (crow + i < M)
                    C[(size_t)(crow + i) * NN + ccol] = acc[m][n][i] + bv[n];
            }
        }
    }
}

// ---------------------------------------------------------------------------
// 4-way batched small GEMM (layer 3, N=32): BM=64 BN=64 BK=16, 4x4/thread
// ---------------------------------------------------------------------------
__global__ __launch_bounds__(256) void gemm4_64(
        const float* __restrict__ A, P4 p, int M, int K, int N) {
    __shared__ float As[16][68];
    __shared__ float Wsm[16][68];
    const float* __restrict__ W    = p.W[blockIdx.z];
    const float* __restrict__ bias = p.B[blockIdx.z];
    float*                    C    = p.C[blockIdx.z];
    const int tid = threadIdx.x;
    const int tx = tid & 15;
    const int ty = tid >> 4;
    const int bm = blockIdx.y * 64;
    const int bn = blockIdx.x * 64;

    float acc[4][4] = {};

    for (int k0 = 0; k0 < K; k0 += 16) {
        {
            int r  = tid >> 2;
            int kk = (tid & 3) * 4;
            float4 v4 = make_float4(0.f,0.f,0.f,0.f);
            if (bm + r < M)
                v4 = *(const float4*)(A + (size_t)(bm + r) * K + k0 + kk);
            As[kk+0][r]=v4.x; As[kk+1][r]=v4.y; As[kk+2][r]=v4.z; As[kk+3][r]=v4.w;
        }
        {
            int kk = tid >> 4;
            int n4 = (tid & 15) * 4;
            float4 v4 = make_float4(0.f,0.f,0.f,0.f);
            if (bn + n4 < N)
                v4 = *(const float4*)(W + (size_t)(k0 + kk) * N + bn + n4);
            *(float4*)&Wsm[kk][n4] = v4;
        }
        __syncthreads();
        #pragma unroll
        for (int kk = 0; kk < 16; kk++) {
            float4 a0 = *(const float4*)&As[kk][ty * 4];
            float4 b0 = *(const float4*)&Wsm[kk][tx * 4];
            float a[4] = {a0.x,a0.y,a0.z,a0.w};
            float b[4] = {b0.x,b0.y,b0.z,b0.w};
            #pragma unroll
            for (int i = 0; i < 4; i++)
                #pragma unroll
                for (int j = 0; j < 4; j++)
                    acc[i][j] += a[i] * b[j];
        }
        __syncthreads();
    }

    #pragma unroll
    for (int i = 0; i < 4; i++) {
        int m = bm + ty * 4 + i;
        if (m >= M) continue;
        #pragma unroll
        for (int j = 0; j < 4; j++) {
            int n = bn + tx * 4 + j;
            if (n < N) C[(size_t)m * N + n] = acc[i][j] + bias[n];
        }
    }
}

// ---------------------------------------------------------------------------
// Fused per-node attention v2: 4-edge unrolled online softmax + skip + ReLU.
// dof threads per node; 32 lanes per head. sk may alias outb.
// OUTBF16: write bf16 hi/lo split (feeds next layer's MFMA GEMM) instead of f32.
// ---------------------------------------------------------------------------
template<bool OUTBF16>
__global__ __launch_bounds__(256) void attn_fused2(
        const float* __restrict__ q, const float* __restrict__ k,
        const float* __restrict__ v, const float* sk,
        const int* __restrict__ offs, const int* __restrict__ srcPerm,
        float* outb, ushort* __restrict__ ohi, ushort* __restrict__ olo,
        int N, int dof, float scale) {
    const int npb = blockDim.x / dof;
    const int sub = threadIdx.x / dof;
    const int j   = threadIdx.x % dof;
    const int n   = blockIdx.x * npb + sub;
    if (n >= N) return;

    const float qj = q[(size_t)n * dof + j];
    float m = -INFINITY, d = 0.f, acc = 0.f;

    const int i0 = offs[n], i1 = offs[n + 1];
    int i = i0;
    for (; i + 4 <= i1; i += 4) {
        const int s0 = srcPerm[i + 0], s1 = srcPerm[i + 1];
        const int s2 = srcPerm[i + 2], s3 = srcPerm[i + 3];
        const float k0 = k[(size_t)s0 * dof + j], v0 = v[(size_t)s0 * dof + j];
        const float k1 = k[(size_t)s1 * dof + j], v1 = v[(size_t)s1 * dof + j];
        const float k2 = k[(size_t)s2 * dof + j], v2 = v[(size_t)s2 * dof + j];
        const float k3 = k[(size_t)s3 * dof + j], v3 = v[(size_t)s3 * dof + j];
        float p0 = qj * k0, p1 = qj * k1, p2 = qj * k2, p3 = qj * k3;
        #pragma unroll
        for (int msk = 16; msk >= 1; msk >>= 1) {
            p0 += __shfl_xor(p0, msk, 32);
            p1 += __shfl_xor(p1, msk, 32);
            p2 += __shfl_xor(p2, msk, 32);
            p3 += __shfl_xor(p3, msk, 32);
        }
        const float sc0 = p0 * scale, sc1 = p1 * scale;
        const float sc2 = p2 * scale, sc3 = p3 * scale;
        const float mx = fmaxf(fmaxf(sc0, sc1), fmaxf(sc2, sc3));
        if (mx > m) {                          // uniform within 32-lane group
            const float r = __expf(m - mx);    // first group: exp(-inf)=0
            acc *= r; d *= r; m = mx;
        }
        const float e0 = __expf(sc0 - m), e1 = __expf(sc1 - m);
        const float e2 = __expf(sc2 - m), e3 = __expf(sc3 - m);
        acc += e0 * v0 + e1 * v1 + e2 * v2 + e3 * v3;
        d   += (e0 + e1) + (e2 + e3);
    }
    for (; i < i1; ++i) {
        const int s = srcPerm[i];
        const float kj = k[(size_t)s * dof + j];
        const float vj = v[(size_t)s * dof + j];
        float prod = qj * kj;
        #pragma unroll
        for (int msk = 16; msk >= 1; msk >>= 1)
            prod += __shfl_xor(prod, msk, 32);
        const float sc = prod * scale;
        if (sc > m) {
            const float r = __expf(m - sc);
            acc *= r; d *= r; m = sc;
        }
        const float p = __expf(sc - m);
        acc += p * vj; d += p;
    }
    float val = acc / (d + 1e-16f) + sk[(size_t)n * dof + j];
    val = val > 0.f ? val : 0.f;
    if (OUTBF16) {
        const size_t o = (size_t)n * dof + j;
        ushort h = f2bf(val);
        ohi[o] = h;
        olo[o] = f2bf(val - bf2f(h));
    } else {
        outb[(size_t)n * dof + j] = val;
    }
}

// ---------------------------------------------------------------------------
// graph boundaries from sorted batch -> gofs[0..G]
// ---------------------------------------------------------------------------
__global__ void graph_offsets(const int* __restrict__ batch, int* __restrict__ gofs,
                              int N, int G) {
    int n = blockIdx.x * blockDim.x + threadIdx.x;
    if (n >= N) return;
    int b = batch[n];
    if (n == 0) { for (int g = 0; g <= b; g++) gofs[g] = 0; }
    else {
        int pb = batch[n - 1];
        if (pb != b) for (int g = pb + 1; g <= b; g++) gofs[g] = n;
    }
    if (n == N - 1) { for (int g = b + 1; g <= G; g++) gofs[g] = N; }
}

// segmented mean-pool: one block per graph, no atomics; writes the MEAN
__global__ __launch_bounds__(1024) void pool_seg(const float* __restrict__ h,
                                                 const int* __restrict__ gofs,
                                                 float* __restrict__ pooled) {
    const int g = blockIdx.x;
    const int j = threadIdx.x & 31;
    const int r = threadIdx.x >> 5;        // 0..31
    const int s0 = gofs[g], s1 = gofs[g + 1];
    float s = 0.f;
    for (int n = s0 + r; n < s1; n += 32) s += h[(size_t)n * HID + j];
    __shared__ float red[32][33];
    red[r][j] = s;
    __syncthreads();
    if (r == 0) {
        float tt = 0.f;
        #pragma unroll
        for (int i = 0; i < 32; i++) tt += red[i][j];
        pooled[g * HID + j] = tt / fmaxf((float)(s1 - s0), 1.f);
    }
}

// logits = pooled_mean @ wlin + blin ; log_softmax
__global__ void head_kernel(const float* __restrict__ pooled,
                            const float* __restrict__ wlin, const float* __restrict__ blin,
                            float* __restrict__ out) {
    int g = threadIdx.x;
    if (g >= GRP) return;
    float logit[OUTC];
    #pragma unroll
    for (int o = 0; o < OUTC; o++) logit[o] = blin[o];
    for (int j = 0; j < HID; j++) {
        float pv = pooled[g * HID + j];
        #pragma unroll
        for (int o = 0; o < OUTC; o++) logit[o] += pv * wlin[j * OUTC + o];
    }
    float mx = logit[0];
    #pragma unroll
    for (int o = 1; o < OUTC; o++) mx = fmaxf(mx, logit[o]);
    float sum = 0.f;
    #pragma unroll
    for (int o = 0; o < OUTC; o++) sum += expf(logit[o] - mx);
    float lse = mx + logf(sum);
    #pragma unroll
    for (int o = 0; o < OUTC; o++) out[g * OUTC + o] = logit[o] - lse;
}

// ---------------------------------------------------------------------------
extern "C" void kernel_launch(void* const* d_in, const int* in_sizes, int n_in,
                              void* d_out, int out_size, void* d_ws, size_t ws_size,
                              hipStream_t stream) {
    const float* x     = (const float*)d_in[0];
    const int*   ei    = (const int*)d_in[1];
    const int*   batch = (const int*)d_in[2];
    const int N = in_sizes[0] / 128;
    const int E = in_sizes[1] / 2;
    const int* src = ei;
    const int* dst = ei + E;

    // setup_inputs dict order per layer: wq, wk, wv, ws, bq, bk, bv, bs
    const float *W[4][4], *B[4][4];
    for (int i = 0; i < 4; i++)
        for (int j = 0; j < 4; j++) {
            W[i][j] = (const float*)d_in[3 + i * 8 + j];
            B[i][j] = (const float*)d_in[3 + i * 8 + 4 + j];
        }
    const float* wlin = (const float*)d_in[35];
    const float* blin = (const float*)d_in[36];

    // ---- workspace carving (bytes) ----
    char* base = (char*)d_ws;
    size_t off = 0;
    auto alloc = [&](size_t bytes) {
        char* p = base + off;
        off = (off + bytes + 255) & ~(size_t)255;
        return p;
    };
    float*  qb   = (float*)alloc((size_t)N * 256 * 4);
    float*  kb   = (float*)alloc((size_t)N * 256 * 4);
    float*  vb   = (float*)alloc((size_t)N * 256 * 4);
    float*  bufA = (float*)alloc((size_t)N * 256 * 4);
    float*  bufB = (float*)alloc((size_t)N * 256 * 4);
    ushort* ahi  = (ushort*)alloc((size_t)N * 256 * 2);
    ushort* alo  = (ushort*)alloc((size_t)N * 256 * 2);
    // Wt splits: L0: 4*256*128 ; L1,L2: 4*256*256 each
    ushort* wth[3], *wtl[3];
    const int Ks[3] = {128, 256, 256};
    for (int L = 0; L < 3; L++) {
        wth[L] = (ushort*)alloc((size_t)4 * 256 * Ks[L] * 2);
        wtl[L] = (ushort*)alloc((size_t)4 * 256 * Ks[L] * 2);
    }
    int*   deg     = (int*)alloc((size_t)N * 4);
    int*   pos     = (int*)alloc((size_t)N * 4);
    int*   offs    = (int*)alloc((size_t)(N + 1) * 4);
    int*   perm    = (int*)alloc((size_t)E * 4);
    int*   srcPerm = (int*)alloc((size_t)E * 4);
    int*   gofs    = (int*)alloc((GRP + 1) * 4);
    float* pooled  = (float*)alloc(GRP * HID * 4);

    // ---- CSR build (once; edge_index constant across layers) ----
    fill_i32<<<(N + 255) / 256, 256, 0, stream>>>(deg, 0, N);
    count_deg<<<(E + 255) / 256, 256, 0, stream>>>(dst, deg, E);
    scan_offsets<<<1, 256, 0, stream>>>(deg, offs, pos, N);
    scatter_edges<<<(E + 255) / 256, 256, 0, stream>>>(dst, pos, perm, E);
    gather_src<<<(E + 255) / 256, 256, 0, stream>>>(perm, src, srcPerm, E);

    // ---- W hi/lo split + transpose (layers 0..2, all z), once ----
    for (int L = 0; L < 3; L++) {
        W4 wp;
        for (int z = 0; z < 4; z++) wp.w[z] = W[L][z];
        dim3 gw((Ks[L] * 256 + 255) / 256, 4);
        splitT_w<<<gw, 256, 0, stream>>>(wp, wth[L], wtl[L], Ks[L]);
    }

    const float scale = 0.17677669529663687f; // 1/sqrt(32)

    // ---- layer 0 input split (x: N x 128) ----
    split_f32<<<(int)(((long long)N * 128 + 255) / 256), 256, 0, stream>>>(
        x, ahi, alo, (long long)N * 128);

    float* skbufs[2] = {bufA, bufB};

    for (int L = 0; L < 3; L++) {
        const int K = Ks[L];
        float* skb = skbufs[L & 1];

        PZmfma p;
        for (int z = 0; z < 4; z++) {
            p.wh[z] = wth[L] + (size_t)z * 256 * K;
            p.wl[z] = wtl[L] + (size_t)z * 256 * K;
            p.bias[z] = B[L][z];
        }
        p.C[0] = qb; p.C[1] = kb; p.C[2] = vb; p.C[3] = skb;
        dim3 gg(2, (N + 127) / 128, 4);
        gemm4_mfma<<<gg, 256, 0, stream>>>(ahi, alo, p, N, K);

        if (L < 2) {
            // attn output feeds only next layer's MFMA GEMM: emit bf16 hi/lo
            attn_fused2<true><<<N, 256, 0, stream>>>(
                qb, kb, vb, skb, offs, srcPerm, nullptr, ahi, alo, N, 256, scale);
        } else {
            // layer-2 output feeds fp32 gemm4_64
            attn_fused2<false><<<N, 256, 0, stream>>>(
                qb, kb, vb, skb, offs, srcPerm, skb, nullptr, nullptr, N, 256, scale);
        }
    }

    // ---- layer 3 (H=1, dof=32, fp32) ----
    {
        const float* cur = skbufs[2 & 1];   // bufA (layer-2 output)
        float* skb = skbufs[1];             // bufB
        P4 p;
        for (int t = 0; t < 4; t++) { p.W[t] = W[3][t]; p.B[t] = B[3][t]; }
        p.C[0] = qb; p.C[1] = kb; p.C[2] = vb; p.C[3] = skb;
        dim3 gg(1, (N + 63) / 64, 4);
        gemm4_64<<<gg, 256, 0, stream>>>(cur, p, N, 256, 32);

        attn_fused2<false><<<(N + 7) / 8, 256, 0, stream>>>(
            qb, kb, vb, skb, offs, srcPerm, skb, nullptr, nullptr, N, 32, scale);

        graph_offsets<<<(N + 255) / 256, 256, 0, stream>>>(batch, gofs, N, GRP);
        pool_seg<<<GRP, 1024, 0, stream>>>(skb, gofs, pooled);
        head_kernel<<<1, 64, 0, stream>>>(pooled, wlin, blin, (float*)d_out);
    }
}

// Round 9
// 723.904 us; speedup vs baseline: 1.8818x; 1.0054x over previous
//
#include <hip/hip_runtime.h>
#include <math.h>

#define HID 32
#define GRP 16
#define OUTC 10

typedef __attribute__((ext_vector_type(8))) short short8;
typedef __attribute__((ext_vector_type(4))) float f32x4;

struct P4     { const float*  W[4]; const float* B[4]; float* C[4]; };
struct W4     { const float*  w[4]; };
struct PZmfma { const ushort* wh[4]; const ushort* wl[4]; const float* bias[4]; float* C[4]; };

// ---------------------------------------------------------------------------
__device__ __forceinline__ ushort f2bf(float f) {
    unsigned u = __float_as_uint(f);
    unsigned r = (u + 0x7FFFu + ((u >> 16) & 1u)) >> 16;   // RNE
    return (ushort)r;
}
__device__ __forceinline__ float bf2f(ushort h) {
    return __uint_as_float(((unsigned)h) << 16);
}

// ---------------------------------------------------------------------------
__global__ void fill_i32(int* p, int v, int n) {
    int i = blockIdx.x * blockDim.x + threadIdx.x;
    if (i < n) p[i] = v;
}

// ---------------------------------------------------------------------------
// CSR build (edge_index is layer-invariant: build once per call)
// ---------------------------------------------------------------------------
__global__ void count_deg(const int* __restrict__ dst, int* __restrict__ deg, int E) {
    int e = blockIdx.x * blockDim.x + threadIdx.x;
    if (e < E) atomicAdd(&deg[dst[e]], 1);
}

__global__ __launch_bounds__(256) void scan_offsets(const int* __restrict__ deg,
                                                    int* __restrict__ offs,
                                                    int* __restrict__ pos, int n) {
    __shared__ int partial[256];
    const int t = threadIdx.x;
    const int chunk = (n + 255) / 256;
    const int start = t * chunk;
    const int end   = min(start + chunk, n);
    int sum = 0;
    for (int i = start; i < end; i++) sum += deg[i];
    partial[t] = sum;
    __syncthreads();
    for (int s = 1; s < 256; s <<= 1) {
        int v = (t >= s) ? partial[t - s] : 0;
        __syncthreads();
        partial[t] += v;
        __syncthreads();
    }
    int base = (t == 0) ? 0 : partial[t - 1];
    for (int i = start; i < end; i++) {
        offs[i] = base; pos[i] = base;
        base += deg[i];
    }
    if (t == 255) offs[n] = base;
}

__global__ void scatter_edges(const int* __restrict__ dst, int* __restrict__ pos,
                              int* __restrict__ perm, int E) {
    int e = blockIdx.x * blockDim.x + threadIdx.x;
    if (e < E) {
        int slot = atomicAdd(&pos[dst[e]], 1);
        perm[slot] = e;
    }
}

__global__ void gather_src(const int* __restrict__ perm, const int* __restrict__ src,
                           int* __restrict__ srcPerm, int E) {
    int i = blockIdx.x * blockDim.x + threadIdx.x;
    if (i < E) srcPerm[i] = src[perm[i]];
}

// ---------------------------------------------------------------------------
// fp32 -> bf16 hi/lo split (elementwise, keeps [M][K] layout)
// ---------------------------------------------------------------------------
__global__ void split_f32(const float* __restrict__ x, ushort* __restrict__ hi,
                          ushort* __restrict__ lo, long long n) {
    long long i = (long long)blockIdx.x * blockDim.x + threadIdx.x;
    if (i >= n) return;
    float v = x[i];
    ushort h = f2bf(v);
    ushort l = f2bf(v - bf2f(h));
    hi[i] = h; lo[i] = l;
}

// W [K][N=256] fp32 -> Wt hi/lo [z][n][k] bf16 (transposed for MFMA B-frag)
__global__ void splitT_w(W4 wp, ushort* __restrict__ wh, ushort* __restrict__ wl, int K) {
    const int NN = 256;
    int z = blockIdx.y;
    const float* W = wp.w[z];
    ushort* whz = wh + (size_t)z * K * NN;
    ushort* wlz = wl + (size_t)z * K * NN;
    int i = blockIdx.x * blockDim.x + threadIdx.x;
    if (i >= K * NN) return;
    int k = i / NN, n = i - k * NN;
    float v = W[i];
    ushort h = f2bf(v);
    ushort l = f2bf(v - bf2f(h));
    whz[(size_t)n * K + k] = h;
    wlz[(size_t)n * K + k] = l;
}

// ---------------------------------------------------------------------------
// MFMA bf16-split GEMM: C[z][M,256] = A[M,K] @ W[z][K,256] + bias[z]
// BM=128 BN=128, 4 waves (2x2), each wave 64x64 = 4x4 frags of 16x16x32.
// A/W pre-split into bf16 hi/lo. 3-product split: hh + hl + lh.
// LDS: 4 x [128][32] bf16 tiles, XOR-swizzled (byte ^= (row&7)<<4).
// ---------------------------------------------------------------------------
#define AHI_OFF 0
#define ALO_OFF 8192
#define BHI_OFF 16384
#define BLO_OFF 24576

__global__ __launch_bounds__(256) void gemm4_mfma(
        const ushort* __restrict__ Ah, const ushort* __restrict__ Al,
        PZmfma p, int M, int K) {
    __shared__ __align__(16) unsigned char smem[32768];
    const int NN = 256;
    const int t  = threadIdx.x;
    const int bn = blockIdx.x * 128;
    const int bm = blockIdx.y * 128;
    const int z  = blockIdx.z;
    const ushort* Wh = p.wh[z];
    const ushort* Wl = p.wl[z];

    const int wid  = t >> 6;
    const int lane = t & 63;
    const int wr = wid >> 1, wc = wid & 1;
    const int l15 = lane & 15, g = lane >> 4;

    f32x4 acc[4][4];
    const f32x4 zero4 = {0.f, 0.f, 0.f, 0.f};
    #pragma unroll
    for (int m = 0; m < 4; m++)
        #pragma unroll
        for (int n = 0; n < 4; n++) acc[m][n] = zero4;

    // staging coords: thread t stages row (t>>1), 32B half (t&1) of each tile
    const int srow = t >> 1;
    const int sseg = t & 1;
    const int o0 = sseg * 2;           // first 16B slot index (of 4 per row)
    // swizzled LDS byte addresses (each slot XORed independently!)
    const int swz = (srow & 7) << 4;
    const int la0 = (srow * 64 + o0 * 16) ^ swz;
    const int la1 = (srow * 64 + (o0 + 1) * 16) ^ swz;
    const bool arow_ok = (bm + srow) < M;
    const size_t abase = (size_t)(bm + srow) * K + sseg * 16;
    const size_t bbase = (size_t)(bn + srow) * K + sseg * 16;

    for (int k0 = 0; k0 < K; k0 += 32) {
        uint4 vah0 = make_uint4(0,0,0,0), vah1 = vah0, val0 = vah0, val1 = vah0;
        if (arow_ok) {
            vah0 = *(const uint4*)(Ah + abase + k0);
            vah1 = *(const uint4*)(Ah + abase + k0 + 8);
            val0 = *(const uint4*)(Al + abase + k0);
            val1 = *(const uint4*)(Al + abase + k0 + 8);
        }
        uint4 vbh0 = *(const uint4*)(Wh + bbase + k0);
        uint4 vbh1 = *(const uint4*)(Wh + bbase + k0 + 8);
        uint4 vbl0 = *(const uint4*)(Wl + bbase + k0);
        uint4 vbl1 = *(const uint4*)(Wl + bbase + k0 + 8);
        __syncthreads();
        *(uint4*)(smem + AHI_OFF + la0) = vah0;
        *(uint4*)(smem + AHI_OFF + la1) = vah1;
        *(uint4*)(smem + ALO_OFF + la0) = val0;
        *(uint4*)(smem + ALO_OFF + la1) = val1;
        *(uint4*)(smem + BHI_OFF + la0) = vbh0;
        *(uint4*)(smem + BHI_OFF + la1) = vbh1;
        *(uint4*)(smem + BLO_OFF + la0) = vbl0;
        *(uint4*)(smem + BLO_OFF + la1) = vbl1;
        __syncthreads();

        // B fragments (cols wc*64 + n*16 + l15, k-octet g)
        short8 bh[4], bl[4];
        #pragma unroll
        for (int n = 0; n < 4; n++) {
            int r  = wc * 64 + n * 16 + l15;
            int ba = (r * 64 + g * 16) ^ ((r & 7) << 4);
            bh[n] = *(const short8*)(smem + BHI_OFF + ba);
            bl[n] = *(const short8*)(smem + BLO_OFF + ba);
        }
        #pragma unroll
        for (int m = 0; m < 4; m++) {
            int r  = wr * 64 + m * 16 + l15;
            int aa = (r * 64 + g * 16) ^ ((r & 7) << 4);
            short8 ah = *(const short8*)(smem + AHI_OFF + aa);
            short8 al = *(const short8*)(smem + ALO_OFF + aa);
            #pragma unroll
            for (int n = 0; n < 4; n++) {
                acc[m][n] = __builtin_amdgcn_mfma_f32_16x16x32_bf16(ah, bh[n], acc[m][n], 0, 0, 0);
                acc[m][n] = __builtin_amdgcn_mfma_f32_16x16x32_bf16(ah, bl[n], acc[m][n], 0, 0, 0);
                acc[m][n] = __builtin_amdgcn_mfma_f32_16x16x32_bf16(al, bh[n], acc[m][n], 0, 0, 0);
            }
        }
    }

    // epilogue: C[row][col], row = bm+wr*64+m*16+g*4+i, col = bn+wc*64+n*16+l15
    float* C = p.C[z];
    const float* bias = p.bias[z];
    float bv[4];
    #pragma unroll
    for (int n = 0; n < 4; n++) bv[n] = bias[bn + wc * 64 + n * 16 + l15];
    #pragma unroll
    for (int m = 0; m < 4; m++) {
        int crow = bm + wr * 64 + m * 16 + g * 4;
        #pragma unroll
        for (int n = 0; n < 4; n++) {
            int ccol = bn + wc * 64 + n * 16 + l15;
            #pragma unroll
            for (int i = 0; i < 4; i++) {
                if (crow + i < M)
                    C[(size_t)(crow + i) * NN + ccol] = acc[m][n][i] + bv[n];
            }
        }
    }
}

// ---------------------------------------------------------------------------
// 4-way batched small GEMM (layer 3, N=32): BM=64 BN=64 BK=16, 4x4/thread
// ---------------------------------------------------------------------------
__global__ __launch_bounds__(256) void gemm4_64(
        const float* __restrict__ A, P4 p, int M, int K, int N) {
    __shared__ float As[16][68];
    __shared__ float Wsm[16][68];
    const float* __restrict__ W    = p.W[blockIdx.z];
    const float* __restrict__ bias = p.B[blockIdx.z];
    float*                    C    = p.C[blockIdx.z];
    const int tid = threadIdx.x;
    const int tx = tid & 15;
    const int ty = tid >> 4;
    const int bm = blockIdx.y * 64;
    const int bn = blockIdx.x * 64;

    float acc[4][4] = {};

    for (int k0 = 0; k0 < K; k0 += 16) {
        {
            int r  = tid >> 2;
            int kk = (tid & 3) * 4;
            float4 v4 = make_float4(0.f,0.f,0.f,0.f);
            if (bm + r < M)
                v4 = *(const float4*)(A + (size_t)(bm + r) * K + k0 + kk);
            As[kk+0][r]=v4.x; As[kk+1][r]=v4.y; As[kk+2][r]=v4.z; As[kk+3][r]=v4.w;
        }
        {
            int kk = tid >> 4;
            int n4 = (tid & 15) * 4;
            float4 v4 = make_float4(0.f,0.f,0.f,0.f);
            if (bn + n4 < N)
                v4 = *(const float4*)(W + (size_t)(k0 + kk) * N + bn + n4);
            *(float4*)&Wsm[kk][n4] = v4;
        }
        __syncthreads();
        #pragma unroll
        for (int kk = 0; kk < 16; kk++) {
            float4 a0 = *(const float4*)&As[kk][ty * 4];
            float4 b0 = *(const float4*)&Wsm[kk][tx * 4];
            float a[4] = {a0.x,a0.y,a0.z,a0.w};
            float b[4] = {b0.x,b0.y,b0.z,b0.w};
            #pragma unroll
            for (int i = 0; i < 4; i++)
                #pragma unroll
                for (int j = 0; j < 4; j++)
                    acc[i][j] += a[i] * b[j];
        }
        __syncthreads();
    }

    #pragma unroll
    for (int i = 0; i < 4; i++) {
        int m = bm + ty * 4 + i;
        if (m >= M) continue;
        #pragma unroll
        for (int j = 0; j < 4; j++) {
            int n = bn + tx * 4 + j;
            if (n < N) C[(size_t)m * N + n] = acc[i][j] + bias[n];
        }
    }
}

// ---------------------------------------------------------------------------
// Fused per-node attention v3: thread-coarsened (float4/thread, 8 lanes/head),
// 4-edge unrolled online softmax + skip + ReLU. sk4 may alias outb.
// OUTBF16: write bf16 hi/lo split (feeds next layer's MFMA GEMM).
// dof4 = dof/4 threads per node; width-8 shuffle reduce per head.
// ---------------------------------------------------------------------------
template<bool OUTBF16>
__global__ __launch_bounds__(256) void attn_fused3(
        const float4* __restrict__ q4, const float4* __restrict__ k4,
        const float4* __restrict__ v4, const float4* sk4,
        const int* __restrict__ offs, const int* __restrict__ srcPerm,
        float4* outb, ushort4* __restrict__ ohi, ushort4* __restrict__ olo,
        int N, int dof4, float scale) {
    const int tpn = dof4;                      // threads per node
    const int npb = blockDim.x / tpn;
    const int sub = threadIdx.x / tpn;
    const int j4  = threadIdx.x % tpn;         // float4 slot within row
    const int n   = blockIdx.x * npb + sub;
    if (n >= N) return;

    const float4 q = q4[(size_t)n * tpn + j4];
    float m = -INFINITY, d = 0.f;
    float ax = 0.f, ay = 0.f, az = 0.f, aw = 0.f;

    const int i0 = offs[n], i1 = offs[n + 1];
    int i = i0;
    for (; i + 4 <= i1; i += 4) {
        const int s0 = srcPerm[i + 0], s1 = srcPerm[i + 1];
        const int s2 = srcPerm[i + 2], s3 = srcPerm[i + 3];
        const float4 ka = k4[(size_t)s0 * tpn + j4], va = v4[(size_t)s0 * tpn + j4];
        const float4 kb = k4[(size_t)s1 * tpn + j4], vb = v4[(size_t)s1 * tpn + j4];
        const float4 kc = k4[(size_t)s2 * tpn + j4], vc = v4[(size_t)s2 * tpn + j4];
        const float4 kd = k4[(size_t)s3 * tpn + j4], vd = v4[(size_t)s3 * tpn + j4];
        float p0 = q.x*ka.x + q.y*ka.y + q.z*ka.z + q.w*ka.w;
        float p1 = q.x*kb.x + q.y*kb.y + q.z*kb.z + q.w*kb.w;
        float p2 = q.x*kc.x + q.y*kc.y + q.z*kc.z + q.w*kc.w;
        float p3 = q.x*kd.x + q.y*kd.y + q.z*kd.z + q.w*kd.w;
        #pragma unroll
        for (int msk = 4; msk >= 1; msk >>= 1) {
            p0 += __shfl_xor(p0, msk, 8);
            p1 += __shfl_xor(p1, msk, 8);
            p2 += __shfl_xor(p2, msk, 8);
            p3 += __shfl_xor(p3, msk, 8);
        }
        const float sc0 = p0 * scale, sc1 = p1 * scale;
        const float sc2 = p2 * scale, sc3 = p3 * scale;
        const float mx = fmaxf(fmaxf(sc0, sc1), fmaxf(sc2, sc3));
        if (mx > m) {                          // uniform within 8-lane group
            const float r = __expf(m - mx);    // first group: exp(-inf)=0
            ax *= r; ay *= r; az *= r; aw *= r; d *= r; m = mx;
        }
        const float e0 = __expf(sc0 - m), e1 = __expf(sc1 - m);
        const float e2 = __expf(sc2 - m), e3 = __expf(sc3 - m);
        ax += e0*va.x + e1*vb.x + e2*vc.x + e3*vd.x;
        ay += e0*va.y + e1*vb.y + e2*vc.y + e3*vd.y;
        az += e0*va.z + e1*vb.z + e2*vc.z + e3*vd.z;
        aw += e0*va.w + e1*vb.w + e2*vc.w + e3*vd.w;
        d  += (e0 + e1) + (e2 + e3);
    }
    for (; i < i1; ++i) {
        const int s = srcPerm[i];
        const float4 kk = k4[(size_t)s * tpn + j4];
        const float4 vv = v4[(size_t)s * tpn + j4];
        float prod = q.x*kk.x + q.y*kk.y + q.z*kk.z + q.w*kk.w;
        #pragma unroll
        for (int msk = 4; msk >= 1; msk >>= 1)
            prod += __shfl_xor(prod, msk, 8);
        const float sc = prod * scale;
        if (sc > m) {
            const float r = __expf(m - sc);
            ax *= r; ay *= r; az *= r; aw *= r; d *= r; m = sc;
        }
        const float p = __expf(sc - m);
        ax += p*vv.x; ay += p*vv.y; az += p*vv.z; aw += p*vv.w;
        d += p;
    }

    const float inv = 1.f / (d + 1e-16f);
    const float4 sk = sk4[(size_t)n * tpn + j4];
    float vx = fmaxf(ax * inv + sk.x, 0.f);
    float vy = fmaxf(ay * inv + sk.y, 0.f);
    float vz = fmaxf(az * inv + sk.z, 0.f);
    float vw = fmaxf(aw * inv + sk.w, 0.f);
    const size_t o = (size_t)n * tpn + j4;
    if (OUTBF16) {
        ushort4 h, l;
        h.x = f2bf(vx); l.x = f2bf(vx - bf2f(h.x));
        h.y = f2bf(vy); l.y = f2bf(vy - bf2f(h.y));
        h.z = f2bf(vz); l.z = f2bf(vz - bf2f(h.z));
        h.w = f2bf(vw); l.w = f2bf(vw - bf2f(h.w));
        ohi[o] = h; olo[o] = l;
    } else {
        outb[o] = make_float4(vx, vy, vz, vw);
    }
}

// ---------------------------------------------------------------------------
// graph boundaries from sorted batch -> gofs[0..G]
// ---------------------------------------------------------------------------
__global__ void graph_offsets(const int* __restrict__ batch, int* __restrict__ gofs,
                              int N, int G) {
    int n = blockIdx.x * blockDim.x + threadIdx.x;
    if (n >= N) return;
    int b = batch[n];
    if (n == 0) { for (int g = 0; g <= b; g++) gofs[g] = 0; }
    else {
        int pb = batch[n - 1];
        if (pb != b) for (int g = pb + 1; g <= b; g++) gofs[g] = n;
    }
    if (n == N - 1) { for (int g = b + 1; g <= G; g++) gofs[g] = N; }
}

// segmented mean-pool: one block per graph, no atomics; writes the MEAN
__global__ __launch_bounds__(1024) void pool_seg(const float* __restrict__ h,
                                                 const int* __restrict__ gofs,
                                                 float* __restrict__ pooled) {
    const int g = blockIdx.x;
    const int j = threadIdx.x & 31;
    const int r = threadIdx.x >> 5;        // 0..31
    const int s0 = gofs[g], s1 = gofs[g + 1];
    float s = 0.f;
    for (int n = s0 + r; n < s1; n += 32) s += h[(size_t)n * HID + j];
    __shared__ float red[32][33];
    red[r][j] = s;
    __syncthreads();
    if (r == 0) {
        float tt = 0.f;
        #pragma unroll
        for (int i = 0; i < 32; i++) tt += red[i][j];
        pooled[g * HID + j] = tt / fmaxf((float)(s1 - s0), 1.f);
    }
}

// logits = pooled_mean @ wlin + blin ; log_softmax
__global__ void head_kernel(const float* __restrict__ pooled,
                            const float* __restrict__ wlin, const float* __restrict__ blin,
                            float* __restrict__ out) {
    int g = threadIdx.x;
    if (g >= GRP) return;
    float logit[OUTC];
    #pragma unroll
    for (int o = 0; o < OUTC; o++) logit[o] = blin[o];
    for (int j = 0; j < HID; j++) {
        float pv = pooled[g * HID + j];
        #pragma unroll
        for (int o = 0; o < OUTC; o++) logit[o] += pv * wlin[j * OUTC + o];
    }
    float mx = logit[0];
    #pragma unroll
    for (int o = 1; o < OUTC; o++) mx = fmaxf(mx, logit[o]);
    float sum = 0.f;
    #pragma unroll
    for (int o = 0; o < OUTC; o++) sum += expf(logit[o] - mx);
    float lse = mx + logf(sum);
    #pragma unroll
    for (int o = 0; o < OUTC; o++) out[g * OUTC + o] = logit[o] - lse;
}

// ---------------------------------------------------------------------------
extern "C" void kernel_launch(void* const* d_in, const int* in_sizes, int n_in,
                              void* d_out, int out_size, void* d_ws, size_t ws_size,
                              hipStream_t stream) {
    const float* x     = (const float*)d_in[0];
    const int*   ei    = (const int*)d_in[1];
    const int*   batch = (const int*)d_in[2];
    const int N = in_sizes[0] / 128;
    const int E = in_sizes[1] / 2;
    const int* src = ei;
    const int* dst = ei + E;

    // setup_inputs dict order per layer: wq, wk, wv, ws, bq, bk, bv, bs
    const float *W[4][4], *B[4][4];
    for (int i = 0; i < 4; i++)
        for (int j = 0; j < 4; j++) {
            W[i][j] = (const float*)d_in[3 + i * 8 + j];
            B[i][j] = (const float*)d_in[3 + i * 8 + 4 + j];
        }
    const float* wlin = (const float*)d_in[35];
    const float* blin = (const float*)d_in[36];

    // ---- workspace carving (bytes) ----
    char* base = (char*)d_ws;
    size_t off = 0;
    auto alloc = [&](size_t bytes) {
        char* p = base + off;
        off = (off + bytes + 255) & ~(size_t)255;
        return p;
    };
    float*  qb   = (float*)alloc((size_t)N * 256 * 4);
    float*  kb   = (float*)alloc((size_t)N * 256 * 4);
    float*  vb   = (float*)alloc((size_t)N * 256 * 4);
    float*  bufA = (float*)alloc((size_t)N * 256 * 4);
    float*  bufB = (float*)alloc((size_t)N * 256 * 4);
    ushort* ahi  = (ushort*)alloc((size_t)N * 256 * 2);
    ushort* alo  = (ushort*)alloc((size_t)N * 256 * 2);
    // Wt splits: L0: 4*256*128 ; L1,L2: 4*256*256 each
    ushort* wth[3], *wtl[3];
    const int Ks[3] = {128, 256, 256};
    for (int L = 0; L < 3; L++) {
        wth[L] = (ushort*)alloc((size_t)4 * 256 * Ks[L] * 2);
        wtl[L] = (ushort*)alloc((size_t)4 * 256 * Ks[L] * 2);
    }
    int*   deg     = (int*)alloc((size_t)N * 4);
    int*   pos     = (int*)alloc((size_t)N * 4);
    int*   offs    = (int*)alloc((size_t)(N + 1) * 4);
    int*   perm    = (int*)alloc((size_t)E * 4);
    int*   srcPerm = (int*)alloc((size_t)E * 4);
    int*   gofs    = (int*)alloc((GRP + 1) * 4);
    float* pooled  = (float*)alloc(GRP * HID * 4);

    // ---- CSR build (once; edge_index constant across layers) ----
    fill_i32<<<(N + 255) / 256, 256, 0, stream>>>(deg, 0, N);
    count_deg<<<(E + 255) / 256, 256, 0, stream>>>(dst, deg, E);
    scan_offsets<<<1, 256, 0, stream>>>(deg, offs, pos, N);
    scatter_edges<<<(E + 255) / 256, 256, 0, stream>>>(dst, pos, perm, E);
    gather_src<<<(E + 255) / 256, 256, 0, stream>>>(perm, src, srcPerm, E);

    // ---- W hi/lo split + transpose (layers 0..2, all z), once ----
    for (int L = 0; L < 3; L++) {
        W4 wp;
        for (int z = 0; z < 4; z++) wp.w[z] = W[L][z];
        dim3 gw((Ks[L] * 256 + 255) / 256, 4);
        splitT_w<<<gw, 256, 0, stream>>>(wp, wth[L], wtl[L], Ks[L]);
    }

    const float scale = 0.17677669529663687f; // 1/sqrt(32)

    // ---- layer 0 input split (x: N x 128) ----
    split_f32<<<(int)(((long long)N * 128 + 255) / 256), 256, 0, stream>>>(
        x, ahi, alo, (long long)N * 128);

    float* skbufs[2] = {bufA, bufB};

    for (int L = 0; L < 3; L++) {
        const int K = Ks[L];
        float* skb = skbufs[L & 1];

        PZmfma p;
        for (int z = 0; z < 4; z++) {
            p.wh[z] = wth[L] + (size_t)z * 256 * K;
            p.wl[z] = wtl[L] + (size_t)z * 256 * K;
            p.bias[z] = B[L][z];
        }
        p.C[0] = qb; p.C[1] = kb; p.C[2] = vb; p.C[3] = skb;
        dim3 gg(2, (N + 127) / 128, 4);
        gemm4_mfma<<<gg, 256, 0, stream>>>(ahi, alo, p, N, K);

        // dof=256 -> dof4=64 threads/node, 4 nodes/block
        if (L < 2) {
            attn_fused3<true><<<(N + 3) / 4, 256, 0, stream>>>(
                (const float4*)qb, (const float4*)kb, (const float4*)vb,
                (const float4*)skb, offs, srcPerm,
                nullptr, (ushort4*)ahi, (ushort4*)alo, N, 64, scale);
        } else {
            attn_fused3<false><<<(N + 3) / 4, 256, 0, stream>>>(
                (const float4*)qb, (const float4*)kb, (const float4*)vb,
                (const float4*)skb, offs, srcPerm,
                (float4*)skb, nullptr, nullptr, N, 64, scale);
        }
    }

    // ---- layer 3 (H=1, dof=32, fp32) ----
    {
        const float* cur = skbufs[2 & 1];   // bufA (layer-2 output)
        float* skb = skbufs[1];             // bufB
        P4 p;
        for (int t = 0; t < 4; t++) { p.W[t] = W[3][t]; p.B[t] = B[3][t]; }
        p.C[0] = qb; p.C[1] = kb; p.C[2] = vb; p.C[3] = skb;
        dim3 gg(1, (N + 63) / 64, 4);
        gemm4_64<<<gg, 256, 0, stream>>>(cur, p, N, 256, 32);

        // dof=32 -> dof4=8 threads/node, 32 nodes/block
        attn_fused3<false><<<(N + 31) / 32, 256, 0, stream>>>(
            (const float4*)qb, (const float4*)kb, (const float4*)vb,
            (const float4*)skb, offs, srcPerm,
            (float4*)skb, nullptr, nullptr, N, 8, scale);

        graph_offsets<<<(N + 255) / 256, 256, 0, stream>>>(batch, gofs, N, GRP);
        pool_seg<<<GRP, 1024, 0, stream>>>(skb, gofs, pooled);
        head_kernel<<<1, 64, 0, stream>>>(pooled, wlin, blin, (float*)d_out);
    }
}

// Round 10
// 599.094 us; speedup vs baseline: 2.2738x; 1.2083x over previous
//
#include <hip/hip_runtime.h>
#include <hip/hip_fp16.h>
#include <math.h>

#define HID 32
#define GRP 16
#define OUTC 10

typedef __attribute__((ext_vector_type(8))) short short8;
typedef __attribute__((ext_vector_type(4))) float f32x4;

struct P4     { const float*  W[4]; const float* B[4]; float* C[4]; __half* kv; };
struct W4     { const float*  w[4]; };
struct PZmfma { const ushort* wh[4]; const ushort* wl[4]; const float* bias[4]; float* C[4]; __half* kv; };

// ---------------------------------------------------------------------------
__device__ __forceinline__ ushort f2bf(float f) {
    unsigned u = __float_as_uint(f);
    unsigned r = (u + 0x7FFFu + ((u >> 16) & 1u)) >> 16;   // RNE
    return (ushort)r;
}
__device__ __forceinline__ float bf2f(ushort h) {
    return __uint_as_float(((unsigned)h) << 16);
}
__device__ __forceinline__ float2 h2f(unsigned u) {
    __half2 h = *reinterpret_cast<__half2*>(&u);
    return __half22float2(h);
}

// ---------------------------------------------------------------------------
__global__ void fill_i32(int* p, int v, int n) {
    int i = blockIdx.x * blockDim.x + threadIdx.x;
    if (i < n) p[i] = v;
}

// ---------------------------------------------------------------------------
// CSR build (edge_index is layer-invariant: build once per call)
// ---------------------------------------------------------------------------
__global__ void count_deg(const int* __restrict__ dst, int* __restrict__ deg, int E) {
    int e = blockIdx.x * blockDim.x + threadIdx.x;
    if (e < E) atomicAdd(&deg[dst[e]], 1);
}

__global__ __launch_bounds__(256) void scan_offsets(const int* __restrict__ deg,
                                                    int* __restrict__ offs,
                                                    int* __restrict__ pos, int n) {
    __shared__ int partial[256];
    const int t = threadIdx.x;
    const int chunk = (n + 255) / 256;
    const int start = t * chunk;
    const int end   = min(start + chunk, n);
    int sum = 0;
    for (int i = start; i < end; i++) sum += deg[i];
    partial[t] = sum;
    __syncthreads();
    for (int s = 1; s < 256; s <<= 1) {
        int v = (t >= s) ? partial[t - s] : 0;
        __syncthreads();
        partial[t] += v;
        __syncthreads();
    }
    int base = (t == 0) ? 0 : partial[t - 1];
    for (int i = start; i < end; i++) {
        offs[i] = base; pos[i] = base;
        base += deg[i];
    }
    if (t == 255) offs[n] = base;
}

__global__ void scatter_edges(const int* __restrict__ dst, int* __restrict__ pos,
                              int* __restrict__ perm, int E) {
    int e = blockIdx.x * blockDim.x + threadIdx.x;
    if (e < E) {
        int slot = atomicAdd(&pos[dst[e]], 1);
        perm[slot] = e;
    }
}

__global__ void gather_src(const int* __restrict__ perm, const int* __restrict__ src,
                           int* __restrict__ srcPerm, int E) {
    int i = blockIdx.x * blockDim.x + threadIdx.x;
    if (i < E) srcPerm[i] = src[perm[i]];
}

// ---------------------------------------------------------------------------
// fp32 -> bf16 hi/lo split (elementwise, keeps [M][K] layout)
// ---------------------------------------------------------------------------
__global__ void split_f32(const float* __restrict__ x, ushort* __restrict__ hi,
                          ushort* __restrict__ lo, long long n) {
    long long i = (long long)blockIdx.x * blockDim.x + threadIdx.x;
    if (i >= n) return;
    float v = x[i];
    ushort h = f2bf(v);
    ushort l = f2bf(v - bf2f(h));
    hi[i] = h; lo[i] = l;
}

// W [K][N=256] fp32 -> Wt hi/lo [z][n][k] bf16 (transposed for MFMA B-frag)
__global__ void splitT_w(W4 wp, ushort* __restrict__ wh, ushort* __restrict__ wl, int K) {
    const int NN = 256;
    int z = blockIdx.y;
    const float* W = wp.w[z];
    ushort* whz = wh + (size_t)z * K * NN;
    ushort* wlz = wl + (size_t)z * K * NN;
    int i = blockIdx.x * blockDim.x + threadIdx.x;
    if (i >= K * NN) return;
    int k = i / NN, n = i - k * NN;
    float v = W[i];
    ushort h = f2bf(v);
    ushort l = f2bf(v - bf2f(h));
    whz[(size_t)n * K + k] = h;
    wlz[(size_t)n * K + k] = l;
}

// ---------------------------------------------------------------------------
// MFMA bf16-split GEMM: C[z][M,256] = A[M,K] @ W[z][K,256] + bias[z]
// z=0 -> fp32 q, z=3 -> fp32 skip, z=1/2 -> fp16 into interleaved kv buffer:
// kv[row][slot] = 16B {k4 (4x fp16), v4 (4x fp16)}, slot = col/4.
// ---------------------------------------------------------------------------
#define AHI_OFF 0
#define ALO_OFF 8192
#define BHI_OFF 16384
#define BLO_OFF 24576

__global__ __launch_bounds__(256) void gemm4_mfma(
        const ushort* __restrict__ Ah, const ushort* __restrict__ Al,
        PZmfma p, int M, int K) {
    __shared__ __align__(16) unsigned char smem[32768];
    const int NN = 256;
    const int t  = threadIdx.x;
    const int bn = blockIdx.x * 128;
    const int bm = blockIdx.y * 128;
    const int z  = blockIdx.z;
    const ushort* Wh = p.wh[z];
    const ushort* Wl = p.wl[z];

    const int wid  = t >> 6;
    const int lane = t & 63;
    const int wr = wid >> 1, wc = wid & 1;
    const int l15 = lane & 15, g = lane >> 4;

    f32x4 acc[4][4];
    const f32x4 zero4 = {0.f, 0.f, 0.f, 0.f};
    #pragma unroll
    for (int m = 0; m < 4; m++)
        #pragma unroll
        for (int n = 0; n < 4; n++) acc[m][n] = zero4;

    // staging coords: thread t stages row (t>>1), 32B half (t&1) of each tile
    const int srow = t >> 1;
    const int sseg = t & 1;
    const int o0 = sseg * 2;           // first 16B slot index (of 4 per row)
    // swizzled LDS byte addresses (each slot XORed independently!)
    const int swz = (srow & 7) << 4;
    const int la0 = (srow * 64 + o0 * 16) ^ swz;
    const int la1 = (srow * 64 + (o0 + 1) * 16) ^ swz;
    const bool arow_ok = (bm + srow) < M;
    const size_t abase = (size_t)(bm + srow) * K + sseg * 16;
    const size_t bbase = (size_t)(bn + srow) * K + sseg * 16;

    for (int k0 = 0; k0 < K; k0 += 32) {
        uint4 vah0 = make_uint4(0,0,0,0), vah1 = vah0, val0 = vah0, val1 = vah0;
        if (arow_ok) {
            vah0 = *(const uint4*)(Ah + abase + k0);
            vah1 = *(const uint4*)(Ah + abase + k0 + 8);
            val0 = *(const uint4*)(Al + abase + k0);
            val1 = *(const uint4*)(Al + abase + k0 + 8);
        }
        uint4 vbh0 = *(const uint4*)(Wh + bbase + k0);
        uint4 vbh1 = *(const uint4*)(Wh + bbase + k0 + 8);
        uint4 vbl0 = *(const uint4*)(Wl + bbase + k0);
        uint4 vbl1 = *(const uint4*)(Wl + bbase + k0 + 8);
        __syncthreads();
        *(uint4*)(smem + AHI_OFF + la0) = vah0;
        *(uint4*)(smem + AHI_OFF + la1) = vah1;
        *(uint4*)(smem + ALO_OFF + la0) = val0;
        *(uint4*)(smem + ALO_OFF + la1) = val1;
        *(uint4*)(smem + BHI_OFF + la0) = vbh0;
        *(uint4*)(smem + BHI_OFF + la1) = vbh1;
        *(uint4*)(smem + BLO_OFF + la0) = vbl0;
        *(uint4*)(smem + BLO_OFF + la1) = vbl1;
        __syncthreads();

        // B fragments (cols wc*64 + n*16 + l15, k-octet g)
        short8 bh[4], bl[4];
        #pragma unroll
        for (int n = 0; n < 4; n++) {
            int r  = wc * 64 + n * 16 + l15;
            int ba = (r * 64 + g * 16) ^ ((r & 7) << 4);
            bh[n] = *(const short8*)(smem + BHI_OFF + ba);
            bl[n] = *(const short8*)(smem + BLO_OFF + ba);
        }
        #pragma unroll
        for (int m = 0; m < 4; m++) {
            int r  = wr * 64 + m * 16 + l15;
            int aa = (r * 64 + g * 16) ^ ((r & 7) << 4);
            short8 ah = *(const short8*)(smem + AHI_OFF + aa);
            short8 al = *(const short8*)(smem + ALO_OFF + aa);
            #pragma unroll
            for (int n = 0; n < 4; n++) {
                acc[m][n] = __builtin_amdgcn_mfma_f32_16x16x32_bf16(ah, bh[n], acc[m][n], 0, 0, 0);
                acc[m][n] = __builtin_amdgcn_mfma_f32_16x16x32_bf16(ah, bl[n], acc[m][n], 0, 0, 0);
                acc[m][n] = __builtin_amdgcn_mfma_f32_16x16x32_bf16(al, bh[n], acc[m][n], 0, 0, 0);
            }
        }
    }

    // epilogue: row = bm+wr*64+m*16+g*4+i, col = bn+wc*64+n*16+l15
    float* C = p.C[z];
    const float* bias = p.bias[z];
    const bool isKV = (z == 1) || (z == 2);
    const int  vOff = (z == 2) ? 4 : 0;
    float bv[4];
    #pragma unroll
    for (int n = 0; n < 4; n++) bv[n] = bias[bn + wc * 64 + n * 16 + l15];
    #pragma unroll
    for (int m = 0; m < 4; m++) {
        int crow = bm + wr * 64 + m * 16 + g * 4;
        #pragma unroll
        for (int n = 0; n < 4; n++) {
            int ccol = bn + wc * 64 + n * 16 + l15;
            #pragma unroll
            for (int i = 0; i < 4; i++) {
                if (crow + i < M) {
                    float val = acc[m][n][i] + bv[n];
                    if (isKV)
                        p.kv[(size_t)(crow + i) * 512 + ((ccol >> 2) << 3) + vOff + (ccol & 3)]
                            = __float2half(val);
                    else
                        C[(size_t)(crow + i) * NN + ccol] = val;
                }
            }
        }
    }
}

// ---------------------------------------------------------------------------
// 4-way batched small GEMM (layer 3, N=32): BM=64 BN=64 BK=16, 4x4/thread
// z=1/2 write fp16 into kv (row stride 64 ushorts at dof=32).
// ---------------------------------------------------------------------------
__global__ __launch_bounds__(256) void gemm4_64(
        const float* __restrict__ A, P4 p, int M, int K, int N) {
    __shared__ float As[16][68];
    __shared__ float Wsm[16][68];
    const float* __restrict__ W    = p.W[blockIdx.z];
    const float* __restrict__ bias = p.B[blockIdx.z];
    float*                    C    = p.C[blockIdx.z];
    const bool isKV = (blockIdx.z == 1) || (blockIdx.z == 2);
    const int  vOff = (blockIdx.z == 2) ? 4 : 0;
    const int tid = threadIdx.x;
    const int tx = tid & 15;
    const int ty = tid >> 4;
    const int bm = blockIdx.y * 64;
    const int bn = blockIdx.x * 64;

    float acc[4][4] = {};

    for (int k0 = 0; k0 < K; k0 += 16) {
        {
            int r  = tid >> 2;
            int kk = (tid & 3) * 4;
            float4 v4 = make_float4(0.f,0.f,0.f,0.f);
            if (bm + r < M)
                v4 = *(const float4*)(A + (size_t)(bm + r) * K + k0 + kk);
            As[kk+0][r]=v4.x; As[kk+1][r]=v4.y; As[kk+2][r]=v4.z; As[kk+3][r]=v4.w;
        }
        {
            int kk = tid >> 4;
            int n4 = (tid & 15) * 4;
            float4 v4 = make_float4(0.f,0.f,0.f,0.f);
            if (bn + n4 < N)
                v4 = *(const float4*)(W + (size_t)(k0 + kk) * N + bn + n4);
            *(float4*)&Wsm[kk][n4] = v4;
        }
        __syncthreads();
        #pragma unroll
        for (int kk = 0; kk < 16; kk++) {
            float4 a0 = *(const float4*)&As[kk][ty * 4];
            float4 b0 = *(const float4*)&Wsm[kk][tx * 4];
            float a[4] = {a0.x,a0.y,a0.z,a0.w};
            float b[4] = {b0.x,b0.y,b0.z,b0.w};
            #pragma unroll
            for (int i = 0; i < 4; i++)
                #pragma unroll
                for (int j = 0; j < 4; j++)
                    acc[i][j] += a[i] * b[j];
        }
        __syncthreads();
    }

    #pragma unroll
    for (int i = 0; i < 4; i++) {
        int m = bm + ty * 4 + i;
        if (m >= M) continue;
        #pragma unroll
        for (int j = 0; j < 4; j++) {
            int n = bn + tx * 4 + j;
            if (n < N) {
                float val = acc[i][j] + bias[n];
                if (isKV)
                    p.kv[(size_t)m * 64 + ((n >> 2) << 3) + vOff + (n & 3)] = __float2half(val);
                else
                    C[(size_t)m * N + n] = val;
            }
        }
    }
}

// ---------------------------------------------------------------------------
// Fused per-node attention v4: fp16 interleaved kv gather (16B = k4+v4),
// float4/thread, width-8 head reduce, 4-edge unrolled online softmax,
// + skip + ReLU. sk4 may alias outb.
// ---------------------------------------------------------------------------
template<bool OUTBF16>
__global__ __launch_bounds__(256) void attn_fused4(
        const float4* __restrict__ q4, const uint4* __restrict__ kv4,
        const float4* sk4, const int* __restrict__ offs, const int* __restrict__ srcPerm,
        float4* outb, ushort4* __restrict__ ohi, ushort4* __restrict__ olo,
        int N, int tpn, float scale) {
    const int npb = blockDim.x / tpn;
    const int sub = threadIdx.x / tpn;
    const int j4  = threadIdx.x % tpn;         // float4 slot within row
    const int n   = blockIdx.x * npb + sub;
    if (n >= N) return;

    const float4 q = q4[(size_t)n * tpn + j4];
    float m = -INFINITY, d = 0.f;
    float ax = 0.f, ay = 0.f, az = 0.f, aw = 0.f;

    const int i0 = offs[n], i1 = offs[n + 1];
    int i = i0;
    for (; i + 4 <= i1; i += 4) {
        const int s0 = srcPerm[i + 0], s1 = srcPerm[i + 1];
        const int s2 = srcPerm[i + 2], s3 = srcPerm[i + 3];
        const uint4 ca = kv4[(size_t)s0 * tpn + j4];
        const uint4 cb = kv4[(size_t)s1 * tpn + j4];
        const uint4 cc = kv4[(size_t)s2 * tpn + j4];
        const uint4 cd = kv4[(size_t)s3 * tpn + j4];
        const float2 ka0 = h2f(ca.x), ka1 = h2f(ca.y);
        const float2 kb0 = h2f(cb.x), kb1 = h2f(cb.y);
        const float2 kc0 = h2f(cc.x), kc1 = h2f(cc.y);
        const float2 kd0 = h2f(cd.x), kd1 = h2f(cd.y);
        float p0 = q.x*ka0.x + q.y*ka0.y + q.z*ka1.x + q.w*ka1.y;
        float p1 = q.x*kb0.x + q.y*kb0.y + q.z*kb1.x + q.w*kb1.y;
        float p2 = q.x*kc0.x + q.y*kc0.y + q.z*kc1.x + q.w*kc1.y;
        float p3 = q.x*kd0.x + q.y*kd0.y + q.z*kd1.x + q.w*kd1.y;
        #pragma unroll
        for (int msk = 4; msk >= 1; msk >>= 1) {
            p0 += __shfl_xor(p0, msk, 8);
            p1 += __shfl_xor(p1, msk, 8);
            p2 += __shfl_xor(p2, msk, 8);
            p3 += __shfl_xor(p3, msk, 8);
        }
        const float sc0 = p0 * scale, sc1 = p1 * scale;
        const float sc2 = p2 * scale, sc3 = p3 * scale;
        const float mx = fmaxf(fmaxf(sc0, sc1), fmaxf(sc2, sc3));
        if (mx > m) {                          // uniform within 8-lane group
            const float r = __expf(m - mx);    // first group: exp(-inf)=0
            ax *= r; ay *= r; az *= r; aw *= r; d *= r; m = mx;
        }
        const float e0 = __expf(sc0 - m), e1 = __expf(sc1 - m);
        const float e2 = __expf(sc2 - m), e3 = __expf(sc3 - m);
        const float2 va0 = h2f(ca.z), va1 = h2f(ca.w);
        const float2 vb0 = h2f(cb.z), vb1 = h2f(cb.w);
        const float2 vc0 = h2f(cc.z), vc1 = h2f(cc.w);
        const float2 vd0 = h2f(cd.z), vd1 = h2f(cd.w);
        ax += e0*va0.x + e1*vb0.x + e2*vc0.x + e3*vd0.x;
        ay += e0*va0.y + e1*vb0.y + e2*vc0.y + e3*vd0.y;
        az += e0*va1.x + e1*vb1.x + e2*vc1.x + e3*vd1.x;
        aw += e0*va1.y + e1*vb1.y + e2*vc1.y + e3*vd1.y;
        d  += (e0 + e1) + (e2 + e3);
    }
    for (; i < i1; ++i) {
        const int s = srcPerm[i];
        const uint4 ce = kv4[(size_t)s * tpn + j4];
        const float2 k0 = h2f(ce.x), k1 = h2f(ce.y);
        float prod = q.x*k0.x + q.y*k0.y + q.z*k1.x + q.w*k1.y;
        #pragma unroll
        for (int msk = 4; msk >= 1; msk >>= 1)
            prod += __shfl_xor(prod, msk, 8);
        const float sc = prod * scale;
        if (sc > m) {
            const float r = __expf(m - sc);
            ax *= r; ay *= r; az *= r; aw *= r; d *= r; m = sc;
        }
        const float p = __expf(sc - m);
        const float2 v0 = h2f(ce.z), v1 = h2f(ce.w);
        ax += p*v0.x; ay += p*v0.y; az += p*v1.x; aw += p*v1.y;
        d += p;
    }

    const float inv = 1.f / (d + 1e-16f);
    const float4 sk = sk4[(size_t)n * tpn + j4];
    float vx = fmaxf(ax * inv + sk.x, 0.f);
    float vy = fmaxf(ay * inv + sk.y, 0.f);
    float vz = fmaxf(az * inv + sk.z, 0.f);
    float vw = fmaxf(aw * inv + sk.w, 0.f);
    const size_t o = (size_t)n * tpn + j4;
    if (OUTBF16) {
        ushort4 h, l;
        h.x = f2bf(vx); l.x = f2bf(vx - bf2f(h.x));
        h.y = f2bf(vy); l.y = f2bf(vy - bf2f(h.y));
        h.z = f2bf(vz); l.z = f2bf(vz - bf2f(h.z));
        h.w = f2bf(vw); l.w = f2bf(vw - bf2f(h.w));
        ohi[o] = h; olo[o] = l;
    } else {
        outb[o] = make_float4(vx, vy, vz, vw);
    }
}

// ---------------------------------------------------------------------------
// graph boundaries from sorted batch -> gofs[0..G]
// ---------------------------------------------------------------------------
__global__ void graph_offsets(const int* __restrict__ batch, int* __restrict__ gofs,
                              int N, int G) {
    int n = blockIdx.x * blockDim.x + threadIdx.x;
    if (n >= N) return;
    int b = batch[n];
    if (n == 0) { for (int g = 0; g <= b; g++) gofs[g] = 0; }
    else {
        int pb = batch[n - 1];
        if (pb != b) for (int g = pb + 1; g <= b; g++) gofs[g] = n;
    }
    if (n == N - 1) { for (int g = b + 1; g <= G; g++) gofs[g] = N; }
}

// segmented mean-pool: one block per graph, no atomics; writes the MEAN
__global__ __launch_bounds__(1024) void pool_seg(const float* __restrict__ h,
                                                 const int* __restrict__ gofs,
                                                 float* __restrict__ pooled) {
    const int g = blockIdx.x;
    const int j = threadIdx.x & 31;
    const int r = threadIdx.x >> 5;        // 0..31
    const int s0 = gofs[g], s1 = gofs[g + 1];
    float s = 0.f;
    for (int n = s0 + r; n < s1; n += 32) s += h[(size_t)n * HID + j];
    __shared__ float red[32][33];
    red[r][j] = s;
    __syncthreads();
    if (r == 0) {
        float tt = 0.f;
        #pragma unroll
        for (int i = 0; i < 32; i++) tt += red[i][j];
        pooled[g * HID + j] = tt / fmaxf((float)(s1 - s0), 1.f);
    }
}

// logits = pooled_mean @ wlin + blin ; log_softmax
__global__ void head_kernel(const float* __restrict__ pooled,
                            const float* __restrict__ wlin, const float* __restrict__ blin,
                            float* __restrict__ out) {
    int g = threadIdx.x;
    if (g >= GRP) return;
    float logit[OUTC];
    #pragma unroll
    for (int o = 0; o < OUTC; o++) logit[o] = blin[o];
    for (int j = 0; j < HID; j++) {
        float pv = pooled[g * HID + j];
        #pragma unroll
        for (int o = 0; o < OUTC; o++) logit[o] += pv * wlin[j * OUTC + o];
    }
    float mx = logit[0];
    #pragma unroll
    for (int o = 1; o < OUTC; o++) mx = fmaxf(mx, logit[o]);
    float sum = 0.f;
    #pragma unroll
    for (int o = 0; o < OUTC; o++) sum += expf(logit[o] - mx);
    float lse = mx + logf(sum);
    #pragma unroll
    for (int o = 0; o < OUTC; o++) out[g * OUTC + o] = logit[o] - lse;
}

// ---------------------------------------------------------------------------
extern "C" void kernel_launch(void* const* d_in, const int* in_sizes, int n_in,
                              void* d_out, int out_size, void* d_ws, size_t ws_size,
                              hipStream_t stream) {
    const float* x     = (const float*)d_in[0];
    const int*   ei    = (const int*)d_in[1];
    const int*   batch = (const int*)d_in[2];
    const int N = in_sizes[0] / 128;
    const int E = in_sizes[1] / 2;
    const int* src = ei;
    const int* dst = ei + E;

    // setup_inputs dict order per layer: wq, wk, wv, ws, bq, bk, bv, bs
    const float *W[4][4], *B[4][4];
    for (int i = 0; i < 4; i++)
        for (int j = 0; j < 4; j++) {
            W[i][j] = (const float*)d_in[3 + i * 8 + j];
            B[i][j] = (const float*)d_in[3 + i * 8 + 4 + j];
        }
    const float* wlin = (const float*)d_in[35];
    const float* blin = (const float*)d_in[36];

    // ---- workspace carving (bytes) ----
    char* base = (char*)d_ws;
    size_t off = 0;
    auto alloc = [&](size_t bytes) {
        char* p = base + off;
        off = (off + bytes + 255) & ~(size_t)255;
        return p;
    };
    float*  qb   = (float*)alloc((size_t)N * 256 * 4);
    __half* kvh  = (__half*)alloc((size_t)N * 512 * 2);   // interleaved fp16 k/v
    float*  bufA = (float*)alloc((size_t)N * 256 * 4);
    float*  bufB = (float*)alloc((size_t)N * 256 * 4);
    ushort* ahi  = (ushort*)alloc((size_t)N * 256 * 2);
    ushort* alo  = (ushort*)alloc((size_t)N * 256 * 2);
    // Wt splits: L0: 4*256*128 ; L1,L2: 4*256*256 each
    ushort* wth[3], *wtl[3];
    const int Ks[3] = {128, 256, 256};
    for (int L = 0; L < 3; L++) {
        wth[L] = (ushort*)alloc((size_t)4 * 256 * Ks[L] * 2);
        wtl[L] = (ushort*)alloc((size_t)4 * 256 * Ks[L] * 2);
    }
    int*   deg     = (int*)alloc((size_t)N * 4);
    int*   pos     = (int*)alloc((size_t)N * 4);
    int*   offs    = (int*)alloc((size_t)(N + 1) * 4);
    int*   perm    = (int*)alloc((size_t)E * 4);
    int*   srcPerm = (int*)alloc((size_t)E * 4);
    int*   gofs    = (int*)alloc((GRP + 1) * 4);
    float* pooled  = (float*)alloc(GRP * HID * 4);

    // ---- CSR build (once; edge_index constant across layers) ----
    fill_i32<<<(N + 255) / 256, 256, 0, stream>>>(deg, 0, N);
    count_deg<<<(E + 255) / 256, 256, 0, stream>>>(dst, deg, E);
    scan_offsets<<<1, 256, 0, stream>>>(deg, offs, pos, N);
    scatter_edges<<<(E + 255) / 256, 256, 0, stream>>>(dst, pos, perm, E);
    gather_src<<<(E + 255) / 256, 256, 0, stream>>>(perm, src, srcPerm, E);

    // ---- W hi/lo split + transpose (layers 0..2, all z), once ----
    for (int L = 0; L < 3; L++) {
        W4 wp;
        for (int z = 0; z < 4; z++) wp.w[z] = W[L][z];
        dim3 gw((Ks[L] * 256 + 255) / 256, 4);
        splitT_w<<<gw, 256, 0, stream>>>(wp, wth[L], wtl[L], Ks[L]);
    }

    const float scale = 0.17677669529663687f; // 1/sqrt(32)

    // ---- layer 0 input split (x: N x 128) ----
    split_f32<<<(int)(((long long)N * 128 + 255) / 256), 256, 0, stream>>>(
        x, ahi, alo, (long long)N * 128);

    float* skbufs[2] = {bufA, bufB};

    for (int L = 0; L < 3; L++) {
        const int K = Ks[L];
        float* skb = skbufs[L & 1];

        PZmfma p;
        for (int z = 0; z < 4; z++) {
            p.wh[z] = wth[L] + (size_t)z * 256 * K;
            p.wl[z] = wtl[L] + (size_t)z * 256 * K;
            p.bias[z] = B[L][z];
        }
        p.C[0] = qb; p.C[1] = nullptr; p.C[2] = nullptr; p.C[3] = skb;
        p.kv = kvh;
        dim3 gg(2, (N + 127) / 128, 4);
        gemm4_mfma<<<gg, 256, 0, stream>>>(ahi, alo, p, N, K);

        // dof=256 -> tpn=64 threads/node, 4 nodes/block
        if (L < 2) {
            attn_fused4<true><<<(N + 3) / 4, 256, 0, stream>>>(
                (const float4*)qb, (const uint4*)kvh, (const float4*)skb,
                offs, srcPerm, nullptr, (ushort4*)ahi, (ushort4*)alo, N, 64, scale);
        } else {
            attn_fused4<false><<<(N + 3) / 4, 256, 0, stream>>>(
                (const float4*)qb, (const uint4*)kvh, (const float4*)skb,
                offs, srcPerm, (float4*)skb, nullptr, nullptr, N, 64, scale);
        }
    }

    // ---- layer 3 (H=1, dof=32) ----
    {
        const float* cur = skbufs[2 & 1];   // bufA (layer-2 output)
        float* skb = skbufs[1];             // bufB
        P4 p;
        for (int t = 0; t < 4; t++) { p.W[t] = W[3][t]; p.B[t] = B[3][t]; }
        p.C[0] = qb; p.C[1] = nullptr; p.C[2] = nullptr; p.C[3] = skb;
        p.kv = kvh;
        dim3 gg(1, (N + 63) / 64, 4);
        gemm4_64<<<gg, 256, 0, stream>>>(cur, p, N, 256, 32);

        // dof=32 -> tpn=8 threads/node, 32 nodes/block
        attn_fused4<false><<<(N + 31) / 32, 256, 0, stream>>>(
            (const float4*)qb, (const uint4*)kvh, (const float4*)skb,
            offs, srcPerm, (float4*)skb, nullptr, nullptr, N, 8, scale);

        graph_offsets<<<(N + 255) / 256, 256, 0, stream>>>(batch, gofs, N, GRP);
        pool_seg<<<GRP, 1024, 0, stream>>>(skb, gofs, pooled);
        head_kernel<<<1, 64, 0, stream>>>(pooled, wlin, blin, (float*)d_out);
    }
}

// Round 11
// 555.334 us; speedup vs baseline: 2.4530x; 1.0788x over previous
//
#include <hip/hip_runtime.h>
#include <hip/hip_fp16.h>
#include <math.h>

#define HID 32
#define GRP 16
#define OUTC 10

typedef __attribute__((ext_vector_type(8))) short short8;
typedef __attribute__((ext_vector_type(4))) float f32x4;

struct W4     { const float*  w[4]; };
struct PZmfma { const ushort* wh[4]; const ushort* wl[4]; const float* bias[4]; float* C[4]; __half* kv; };

// ---------------------------------------------------------------------------
__device__ __forceinline__ ushort f2bf(float f) {
    unsigned u = __float_as_uint(f);
    unsigned r = (u + 0x7FFFu + ((u >> 16) & 1u)) >> 16;   // RNE
    return (ushort)r;
}
__device__ __forceinline__ float bf2f(ushort h) {
    return __uint_as_float(((unsigned)h) << 16);
}
__device__ __forceinline__ float2 h2f(unsigned u) {
    __half2 h = *reinterpret_cast<__half2*>(&u);
    return __half22float2(h);
}

// ---------------------------------------------------------------------------
__global__ void fill_i32(int* p, int v, int n) {
    int i = blockIdx.x * blockDim.x + threadIdx.x;
    if (i < n) p[i] = v;
}

// ---------------------------------------------------------------------------
// CSR build (edge_index is layer-invariant: build once per call)
// ---------------------------------------------------------------------------
__global__ void count_deg(const int* __restrict__ dst, int* __restrict__ deg, int E) {
    int e = blockIdx.x * blockDim.x + threadIdx.x;
    if (e < E) atomicAdd(&deg[dst[e]], 1);
}

__global__ __launch_bounds__(256) void scan_offsets(const int* __restrict__ deg,
                                                    int* __restrict__ offs,
                                                    int* __restrict__ pos, int n) {
    __shared__ int partial[256];
    const int t = threadIdx.x;
    const int chunk = (n + 255) / 256;
    const int start = t * chunk;
    const int end   = min(start + chunk, n);
    int sum = 0;
    for (int i = start; i < end; i++) sum += deg[i];
    partial[t] = sum;
    __syncthreads();
    for (int s = 1; s < 256; s <<= 1) {
        int v = (t >= s) ? partial[t - s] : 0;
        __syncthreads();
        partial[t] += v;
        __syncthreads();
    }
    int base = (t == 0) ? 0 : partial[t - 1];
    for (int i = start; i < end; i++) {
        offs[i] = base; pos[i] = base;
        base += deg[i];
    }
    if (t == 255) offs[n] = base;
}

__global__ void scatter_edges(const int* __restrict__ dst, int* __restrict__ pos,
                              int* __restrict__ perm, int E) {
    int e = blockIdx.x * blockDim.x + threadIdx.x;
    if (e < E) {
        int slot = atomicAdd(&pos[dst[e]], 1);
        perm[slot] = e;
    }
}

__global__ void gather_src(const int* __restrict__ perm, const int* __restrict__ src,
                           int* __restrict__ srcPerm, int E) {
    int i = blockIdx.x * blockDim.x + threadIdx.x;
    if (i < E) srcPerm[i] = src[perm[i]];
}

// ---------------------------------------------------------------------------
// fp32 -> bf16 hi/lo split (elementwise, keeps [M][K] layout)
// ---------------------------------------------------------------------------
__global__ void split_f32(const float* __restrict__ x, ushort* __restrict__ hi,
                          ushort* __restrict__ lo, long long n) {
    long long i = (long long)blockIdx.x * blockDim.x + threadIdx.x;
    if (i >= n) return;
    float v = x[i];
    ushort h = f2bf(v);
    ushort l = f2bf(v - bf2f(h));
    hi[i] = h; lo[i] = l;
}

// W [K][NN] fp32 -> Wt hi/lo [z][n][k] bf16 (transposed for MFMA B-frag)
__global__ void splitT_w(W4 wp, ushort* __restrict__ wh, ushort* __restrict__ wl,
                         int K, int NN) {
    int z = blockIdx.y;
    const float* W = wp.w[z];
    ushort* whz = wh + (size_t)z * K * NN;
    ushort* wlz = wl + (size_t)z * K * NN;
    int i = blockIdx.x * blockDim.x + threadIdx.x;
    if (i >= K * NN) return;
    int k = i / NN, n = i - k * NN;
    float v = W[i];
    ushort h = f2bf(v);
    ushort l = f2bf(v - bf2f(h));
    whz[(size_t)n * K + k] = h;
    wlz[(size_t)n * K + k] = l;
}

// ---------------------------------------------------------------------------
// MFMA bf16-split GEMM: C[z][M,256] = A[M,K] @ W[z][K,256] + bias[z]
// BM=128 BN=128, 4 waves (2x2). 3-product split: hh + hl + lh.
// 1D grid, XCD-chunked: w = (bid%8)*(nwg/8) + bid/8; w -> bm(slow),bn,z(fast)
// so the 8 blocks sharing an A-tile land on one XCD (L2 reuse).
// Register prefetch: k-step i+1 global loads issue before i's MFMA phase.
// z=0 -> fp32 q, z=3 -> fp32 skip, z=1/2 -> fp16 interleaved kv
// (kv[row][slot] = 16B {k4, v4}, slot = col/4).
// ---------------------------------------------------------------------------
#define AHI_OFF 0
#define ALO_OFF 8192
#define BHI_OFF 16384
#define BLO_OFF 24576

template<int K>
__global__ __launch_bounds__(256) void gemm4_mfma(
        const ushort* __restrict__ Ah, const ushort* __restrict__ Al,
        PZmfma p, int M) {
    __shared__ __align__(16) unsigned char smem[32768];
    const int NN = 256;
    const int t  = threadIdx.x;
    // XCD chunking (gridDim.x % 8 == 0)
    const int hb  = blockIdx.x;
    const int cpx = gridDim.x >> 3;
    const int w   = (hb & 7) * cpx + (hb >> 3);
    const int bm  = (w >> 3) * 128;
    const int bn  = ((w >> 2) & 1) * 128;
    const int z   = w & 3;
    const ushort* Wh = p.wh[z];
    const ushort* Wl = p.wl[z];

    const int wid  = t >> 6;
    const int lane = t & 63;
    const int wr = wid >> 1, wc = wid & 1;
    const int l15 = lane & 15, g = lane >> 4;

    f32x4 acc[4][4];
    const f32x4 zero4 = {0.f, 0.f, 0.f, 0.f};
    #pragma unroll
    for (int m = 0; m < 4; m++)
        #pragma unroll
        for (int n = 0; n < 4; n++) acc[m][n] = zero4;

    // staging coords: thread t stages row (t>>1), 32B half (t&1) of each tile
    const int srow = t >> 1;
    const int sseg = t & 1;
    const int swz = (srow & 7) << 4;
    const int la0 = (srow * 64 + sseg * 32) ^ swz;
    const int la1 = (srow * 64 + sseg * 32 + 16) ^ swz;
    const bool arow_ok = (bm + srow) < M;
    const size_t abase = (size_t)(bm + srow) * K + sseg * 16;
    const size_t bbase = (size_t)(bn + srow) * K + sseg * 16;

    uint4 ra0, ra1, ra2, ra3, rb0, rb1, rb2, rb3;
    auto loadAB = [&](int k0) {
        ra0 = make_uint4(0,0,0,0); ra1 = ra0; ra2 = ra0; ra3 = ra0;
        if (arow_ok) {
            ra0 = *(const uint4*)(Ah + abase + k0);
            ra1 = *(const uint4*)(Ah + abase + k0 + 8);
            ra2 = *(const uint4*)(Al + abase + k0);
            ra3 = *(const uint4*)(Al + abase + k0 + 8);
        }
        rb0 = *(const uint4*)(Wh + bbase + k0);
        rb1 = *(const uint4*)(Wh + bbase + k0 + 8);
        rb2 = *(const uint4*)(Wl + bbase + k0);
        rb3 = *(const uint4*)(Wl + bbase + k0 + 8);
    };

    loadAB(0);

    #pragma unroll
    for (int ks = 0; ks < K / 32; ks++) {
        __syncthreads();                       // prior frag reads complete
        *(uint4*)(smem + AHI_OFF + la0) = ra0;
        *(uint4*)(smem + AHI_OFF + la1) = ra1;
        *(uint4*)(smem + ALO_OFF + la0) = ra2;
        *(uint4*)(smem + ALO_OFF + la1) = ra3;
        *(uint4*)(smem + BHI_OFF + la0) = rb0;
        *(uint4*)(smem + BHI_OFF + la1) = rb1;
        *(uint4*)(smem + BLO_OFF + la0) = rb2;
        *(uint4*)(smem + BLO_OFF + la1) = rb3;
        __syncthreads();
        if (ks + 1 < K / 32) loadAB((ks + 1) * 32);   // prefetch overlaps MFMA

        short8 bh[4], bl[4];
        #pragma unroll
        for (int n = 0; n < 4; n++) {
            int r  = wc * 64 + n * 16 + l15;
            int ba = (r * 64 + g * 16) ^ ((r & 7) << 4);
            bh[n] = *(const short8*)(smem + BHI_OFF + ba);
            bl[n] = *(const short8*)(smem + BLO_OFF + ba);
        }
        #pragma unroll
        for (int m = 0; m < 4; m++) {
            int r  = wr * 64 + m * 16 + l15;
            int aa = (r * 64 + g * 16) ^ ((r & 7) << 4);
            short8 ah = *(const short8*)(smem + AHI_OFF + aa);
            short8 al = *(const short8*)(smem + ALO_OFF + aa);
            #pragma unroll
            for (int n = 0; n < 4; n++) {
                acc[m][n] = __builtin_amdgcn_mfma_f32_16x16x32_bf16(ah, bh[n], acc[m][n], 0, 0, 0);
                acc[m][n] = __builtin_amdgcn_mfma_f32_16x16x32_bf16(ah, bl[n], acc[m][n], 0, 0, 0);
                acc[m][n] = __builtin_amdgcn_mfma_f32_16x16x32_bf16(al, bh[n], acc[m][n], 0, 0, 0);
            }
        }
    }

    // epilogue: row = bm+wr*64+m*16+g*4+i, col = bn+wc*64+n*16+l15
    float* C = p.C[z];
    const float* bias = p.bias[z];
    const bool isKV = (z == 1) || (z == 2);
    const int  vOff = (z == 2) ? 4 : 0;
    float bv[4];
    #pragma unroll
    for (int n = 0; n < 4; n++) bv[n] = bias[bn + wc * 64 + n * 16 + l15];
    #pragma unroll
    for (int m = 0; m < 4; m++) {
        int crow = bm + wr * 64 + m * 16 + g * 4;
        #pragma unroll
        for (int n = 0; n < 4; n++) {
            int ccol = bn + wc * 64 + n * 16 + l15;
            #pragma unroll
            for (int i = 0; i < 4; i++) {
                if (crow + i < M) {
                    float val = acc[m][n][i] + bv[n];
                    if (isKV)
                        p.kv[(size_t)(crow + i) * 512 + ((ccol >> 2) << 3) + vOff + (ccol & 3)]
                            = __float2half(val);
                    else
                        C[(size_t)(crow + i) * NN + ccol] = val;
                }
            }
        }
    }
}

// ---------------------------------------------------------------------------
// Layer-3 MFMA GEMM: C[z][M,32] = A[M,256] @ W[z][256,32] + bias[z]
// BM=128 BN=32, 4 waves (wave wid -> rows wid*32..+31), 2x2 frags/wave.
// Same staging/swizzle/frag formulas as gemm4_mfma. XCD-chunked grid (padded).
// z=0 -> fp32 q [M,32]; z=3 -> fp32 skip; z=1/2 -> fp16 kv (row stride 64).
// ---------------------------------------------------------------------------
#define A32HI_OFF 0
#define A32LO_OFF 8192
#define B32HI_OFF 16384
#define B32LO_OFF 18432

template<int K>
__global__ __launch_bounds__(256) void gemm4_mfma32(
        const ushort* __restrict__ Ah, const ushort* __restrict__ Al,
        PZmfma p, int M, int nWork) {
    __shared__ __align__(16) unsigned char smem[20480];
    const int t  = threadIdx.x;
    const int hb  = blockIdx.x;
    const int cpx = gridDim.x >> 3;
    const int w   = (hb & 7) * cpx + (hb >> 3);
    if (w >= nWork) return;                    // block-uniform: safe w/ barriers
    const int bm = (w >> 2) * 128;
    const int z  = w & 3;
    const ushort* Wh = p.wh[z];
    const ushort* Wl = p.wl[z];

    const int wid  = t >> 6;
    const int lane = t & 63;
    const int l15 = lane & 15, g = lane >> 4;

    f32x4 acc[2][2];
    const f32x4 zero4 = {0.f, 0.f, 0.f, 0.f};
    acc[0][0] = zero4; acc[0][1] = zero4; acc[1][0] = zero4; acc[1][1] = zero4;

    // A staging: 128 rows x 32 k, thread t -> row t>>1, 32B half t&1
    const int srow = t >> 1;
    const int sseg = t & 1;
    const int swz  = (srow & 7) << 4;
    const int la0 = (srow * 64 + sseg * 32) ^ swz;
    const int la1 = (srow * 64 + sseg * 32 + 16) ^ swz;
    const bool arow_ok = (bm + srow) < M;
    const size_t abase = (size_t)(bm + srow) * K + sseg * 16;
    // B staging: 32 rows x 32 k, threads 0..63 only
    const bool doB = (t < 64);
    const int brow = t >> 1;                   // valid when doB (0..31)
    const int bswz = (brow & 7) << 4;
    const int lb0 = (brow * 64 + sseg * 32) ^ bswz;
    const int lb1 = (brow * 64 + sseg * 32 + 16) ^ bswz;
    const size_t bbase = (size_t)brow * K + sseg * 16;

    uint4 ra0, ra1, ra2, ra3, rb0, rb1, rb2, rb3;
    auto loadAB = [&](int k0) {
        ra0 = make_uint4(0,0,0,0); ra1 = ra0; ra2 = ra0; ra3 = ra0;
        if (arow_ok) {
            ra0 = *(const uint4*)(Ah + abase + k0);
            ra1 = *(const uint4*)(Ah + abase + k0 + 8);
            ra2 = *(const uint4*)(Al + abase + k0);
            ra3 = *(const uint4*)(Al + abase + k0 + 8);
        }
        if (doB) {
            rb0 = *(const uint4*)(Wh + bbase + k0);
            rb1 = *(const uint4*)(Wh + bbase + k0 + 8);
            rb2 = *(const uint4*)(Wl + bbase + k0);
            rb3 = *(const uint4*)(Wl + bbase + k0 + 8);
        }
    };

    loadAB(0);

    #pragma unroll
    for (int ks = 0; ks < K / 32; ks++) {
        __syncthreads();
        *(uint4*)(smem + A32HI_OFF + la0) = ra0;
        *(uint4*)(smem + A32HI_OFF + la1) = ra1;
        *(uint4*)(smem + A32LO_OFF + la0) = ra2;
        *(uint4*)(smem + A32LO_OFF + la1) = ra3;
        if (doB) {
            *(uint4*)(smem + B32HI_OFF + lb0) = rb0;
            *(uint4*)(smem + B32HI_OFF + lb1) = rb1;
            *(uint4*)(smem + B32LO_OFF + lb0) = rb2;
            *(uint4*)(smem + B32LO_OFF + lb1) = rb3;
        }
        __syncthreads();
        if (ks + 1 < K / 32) loadAB((ks + 1) * 32);

        short8 bh[2], bl[2];
        #pragma unroll
        for (int n = 0; n < 2; n++) {
            int r  = n * 16 + l15;
            int ba = (r * 64 + g * 16) ^ ((r & 7) << 4);
            bh[n] = *(const short8*)(smem + B32HI_OFF + ba);
            bl[n] = *(const short8*)(smem + B32LO_OFF + ba);
        }
        #pragma unroll
        for (int m = 0; m < 2; m++) {
            int r  = wid * 32 + m * 16 + l15;
            int aa = (r * 64 + g * 16) ^ ((r & 7) << 4);
            short8 ah = *(const short8*)(smem + A32HI_OFF + aa);
            short8 al = *(const short8*)(smem + A32LO_OFF + aa);
            #pragma unroll
            for (int n = 0; n < 2; n++) {
                acc[m][n] = __builtin_amdgcn_mfma_f32_16x16x32_bf16(ah, bh[n], acc[m][n], 0, 0, 0);
                acc[m][n] = __builtin_amdgcn_mfma_f32_16x16x32_bf16(ah, bl[n], acc[m][n], 0, 0, 0);
                acc[m][n] = __builtin_amdgcn_mfma_f32_16x16x32_bf16(al, bh[n], acc[m][n], 0, 0, 0);
            }
        }
    }

    float* C = p.C[z];
    const float* bias = p.bias[z];
    const bool isKV = (z == 1) || (z == 2);
    const int  vOff = (z == 2) ? 4 : 0;
    float bv[2];
    bv[0] = bias[l15]; bv[1] = bias[16 + l15];
    #pragma unroll
    for (int m = 0; m < 2; m++) {
        int crow = bm + wid * 32 + m * 16 + g * 4;
        #pragma unroll
        for (int n = 0; n < 2; n++) {
            int ccol = n * 16 + l15;
            #pragma unroll
            for (int i = 0; i < 4; i++) {
                if (crow + i < M) {
                    float val = acc[m][n][i] + bv[n];
                    if (isKV)
                        p.kv[(size_t)(crow + i) * 64 + ((ccol >> 2) << 3) + vOff + (ccol & 3)]
                            = __float2half(val);
                    else
                        C[(size_t)(crow + i) * 32 + ccol] = val;
                }
            }
        }
    }
}

// ---------------------------------------------------------------------------
// Fused per-node attention v4: fp16 interleaved kv gather (16B = k4+v4),
// float4/thread, width-8 head reduce, 4-edge unrolled online softmax,
// + skip + ReLU. sk4 may alias outb.
// ---------------------------------------------------------------------------
template<bool OUTBF16>
__global__ __launch_bounds__(256) void attn_fused4(
        const float4* __restrict__ q4, const uint4* __restrict__ kv4,
        const float4* sk4, const int* __restrict__ offs, const int* __restrict__ srcPerm,
        float4* outb, ushort4* __restrict__ ohi, ushort4* __restrict__ olo,
        int N, int tpn, float scale) {
    const int npb = blockDim.x / tpn;
    const int sub = threadIdx.x / tpn;
    const int j4  = threadIdx.x % tpn;         // float4 slot within row
    const int n   = blockIdx.x * npb + sub;
    if (n >= N) return;

    const float4 q = q4[(size_t)n * tpn + j4];
    float m = -INFINITY, d = 0.f;
    float ax = 0.f, ay = 0.f, az = 0.f, aw = 0.f;

    const int i0 = offs[n], i1 = offs[n + 1];
    int i = i0;
    for (; i + 4 <= i1; i += 4) {
        const int s0 = srcPerm[i + 0], s1 = srcPerm[i + 1];
        const int s2 = srcPerm[i + 2], s3 = srcPerm[i + 3];
        const uint4 ca = kv4[(size_t)s0 * tpn + j4];
        const uint4 cb = kv4[(size_t)s1 * tpn + j4];
        const uint4 cc = kv4[(size_t)s2 * tpn + j4];
        const uint4 cd = kv4[(size_t)s3 * tpn + j4];
        const float2 ka0 = h2f(ca.x), ka1 = h2f(ca.y);
        const float2 kb0 = h2f(cb.x), kb1 = h2f(cb.y);
        const float2 kc0 = h2f(cc.x), kc1 = h2f(cc.y);
        const float2 kd0 = h2f(cd.x), kd1 = h2f(cd.y);
        float p0 = q.x*ka0.x + q.y*ka0.y + q.z*ka1.x + q.w*ka1.y;
        float p1 = q.x*kb0.x + q.y*kb0.y + q.z*kb1.x + q.w*kb1.y;
        float p2 = q.x*kc0.x + q.y*kc0.y + q.z*kc1.x + q.w*kc1.y;
        float p3 = q.x*kd0.x + q.y*kd0.y + q.z*kd1.x + q.w*kd1.y;
        #pragma unroll
        for (int msk = 4; msk >= 1; msk >>= 1) {
            p0 += __shfl_xor(p0, msk, 8);
            p1 += __shfl_xor(p1, msk, 8);
            p2 += __shfl_xor(p2, msk, 8);
            p3 += __shfl_xor(p3, msk, 8);
        }
        const float sc0 = p0 * scale, sc1 = p1 * scale;
        const float sc2 = p2 * scale, sc3 = p3 * scale;
        const float mx = fmaxf(fmaxf(sc0, sc1), fmaxf(sc2, sc3));
        if (mx > m) {                          // uniform within 8-lane group
            const float r = __expf(m - mx);    // first group: exp(-inf)=0
            ax *= r; ay *= r; az *= r; aw *= r; d *= r; m = mx;
        }
        const float e0 = __expf(sc0 - m), e1 = __expf(sc1 - m);
        const float e2 = __expf(sc2 - m), e3 = __expf(sc3 - m);
        const float2 va0 = h2f(ca.z), va1 = h2f(ca.w);
        const float2 vb0 = h2f(cb.z), vb1 = h2f(cb.w);
        const float2 vc0 = h2f(cc.z), vc1 = h2f(cc.w);
        const float2 vd0 = h2f(cd.z), vd1 = h2f(cd.w);
        ax += e0*va0.x + e1*vb0.x + e2*vc0.x + e3*vd0.x;
        ay += e0*va0.y + e1*vb0.y + e2*vc0.y + e3*vd0.y;
        az += e0*va1.x + e1*vb1.x + e2*vc1.x + e3*vd1.x;
        aw += e0*va1.y + e1*vb1.y + e2*vc1.y + e3*vd1.y;
        d  += (e0 + e1) + (e2 + e3);
    }
    for (; i < i1; ++i) {
        const int s = srcPerm[i];
        const uint4 ce = kv4[(size_t)s * tpn + j4];
        const float2 k0 = h2f(ce.x), k1 = h2f(ce.y);
        float prod = q.x*k0.x + q.y*k0.y + q.z*k1.x + q.w*k1.y;
        #pragma unroll
        for (int msk = 4; msk >= 1; msk >>= 1)
            prod += __shfl_xor(prod, msk, 8);
        const float sc = prod * scale;
        if (sc > m) {
            const float r = __expf(m - sc);
            ax *= r; ay *= r; az *= r; aw *= r; d *= r; m = sc;
        }
        const float p = __expf(sc - m);
        const float2 v0 = h2f(ce.z), v1 = h2f(ce.w);
        ax += p*v0.x; ay += p*v0.y; az += p*v1.x; aw += p*v1.y;
        d += p;
    }

    const float inv = 1.f / (d + 1e-16f);
    const float4 sk = sk4[(size_t)n * tpn + j4];
    float vx = fmaxf(ax * inv + sk.x, 0.f);
    float vy = fmaxf(ay * inv + sk.y, 0.f);
    float vz = fmaxf(az * inv + sk.z, 0.f);
    float vw = fmaxf(aw * inv + sk.w, 0.f);
    const size_t o = (size_t)n * tpn + j4;
    if (OUTBF16) {
        ushort4 h, l;
        h.x = f2bf(vx); l.x = f2bf(vx - bf2f(h.x));
        h.y = f2bf(vy); l.y = f2bf(vy - bf2f(h.y));
        h.z = f2bf(vz); l.z = f2bf(vz - bf2f(h.z));
        h.w = f2bf(vw); l.w = f2bf(vw - bf2f(h.w));
        ohi[o] = h; olo[o] = l;
    } else {
        outb[o] = make_float4(vx, vy, vz, vw);
    }
}

// ---------------------------------------------------------------------------
// graph boundaries from sorted batch -> gofs[0..G]
// ---------------------------------------------------------------------------
__global__ void graph_offsets(const int* __restrict__ batch, int* __restrict__ gofs,
                              int N, int G) {
    int n = blockIdx.x * blockDim.x + threadIdx.x;
    if (n >= N) return;
    int b = batch[n];
    if (n == 0) { for (int g = 0; g <= b; g++) gofs[g] = 0; }
    else {
        int pb = batch[n - 1];
        if (pb != b) for (int g = pb + 1; g <= b; g++) gofs[g] = n;
    }
    if (n == N - 1) { for (int g = b + 1; g <= G; g++) gofs[g] = N; }
}

// segmented mean-pool: one block per graph, no atomics; writes the MEAN
__global__ __launch_bounds__(1024) void pool_seg(const float* __restrict__ h,
                                                 const int* __restrict__ gofs,
                                                 float* __restrict__ pooled) {
    const int g = blockIdx.x;
    const int j = threadIdx.x & 31;
    const int r = threadIdx.x >> 5;        // 0..31
    const int s0 = gofs[g], s1 = gofs[g + 1];
    float s = 0.f;
    for (int n = s0 + r; n < s1; n += 32) s += h[(size_t)n * HID + j];
    __shared__ float red[32][33];
    red[r][j] = s;
    __syncthreads();
    if (r == 0) {
        float tt = 0.f;
        #pragma unroll
        for (int i = 0; i < 32; i++) tt += red[i][j];
        pooled[g * HID + j] = tt / fmaxf((float)(s1 - s0), 1.f);
    }
}

// logits = pooled_mean @ wlin + blin ; log_softmax
__global__ void head_kernel(const float* __restrict__ pooled,
                            const float* __restrict__ wlin, const float* __restrict__ blin,
                            float* __restrict__ out) {
    int g = threadIdx.x;
    if (g >= GRP) return;
    float logit[OUTC];
    #pragma unroll
    for (int o = 0; o < OUTC; o++) logit[o] = blin[o];
    for (int j = 0; j < HID; j++) {
        float pv = pooled[g * HID + j];
        #pragma unroll
        for (int o = 0; o < OUTC; o++) logit[o] += pv * wlin[j * OUTC + o];
    }
    float mx = logit[0];
    #pragma unroll
    for (int o = 1; o < OUTC; o++) mx = fmaxf(mx, logit[o]);
    float sum = 0.f;
    #pragma unroll
    for (int o = 0; o < OUTC; o++) sum += expf(logit[o] - mx);
    float lse = mx + logf(sum);
    #pragma unroll
    for (int o = 0; o < OUTC; o++) out[g * OUTC + o] = logit[o] - lse;
}

// ---------------------------------------------------------------------------
extern "C" void kernel_launch(void* const* d_in, const int* in_sizes, int n_in,
                              void* d_out, int out_size, void* d_ws, size_t ws_size,
                              hipStream_t stream) {
    const float* x     = (const float*)d_in[0];
    const int*   ei    = (const int*)d_in[1];
    const int*   batch = (const int*)d_in[2];
    const int N = in_sizes[0] / 128;
    const int E = in_sizes[1] / 2;
    const int* src = ei;
    const int* dst = ei + E;

    // setup_inputs dict order per layer: wq, wk, wv, ws, bq, bk, bv, bs
    const float *W[4][4], *B[4][4];
    for (int i = 0; i < 4; i++)
        for (int j = 0; j < 4; j++) {
            W[i][j] = (const float*)d_in[3 + i * 8 + j];
            B[i][j] = (const float*)d_in[3 + i * 8 + 4 + j];
        }
    const float* wlin = (const float*)d_in[35];
    const float* blin = (const float*)d_in[36];

    // ---- workspace carving (bytes) ----
    char* base = (char*)d_ws;
    size_t off = 0;
    auto alloc = [&](size_t bytes) {
        char* p = base + off;
        off = (off + bytes + 255) & ~(size_t)255;
        return p;
    };
    float*  qb   = (float*)alloc((size_t)N * 256 * 4);
    __half* kvh  = (__half*)alloc((size_t)N * 512 * 2);   // interleaved fp16 k/v
    float*  bufA = (float*)alloc((size_t)N * 256 * 4);
    float*  bufB = (float*)alloc((size_t)N * 256 * 4);
    ushort* ahi  = (ushort*)alloc((size_t)N * 256 * 2);
    ushort* alo  = (ushort*)alloc((size_t)N * 256 * 2);
    // Wt splits: L0: 4*256*128 ; L1,L2: 4*256*256 ; L3: 4*32*256
    ushort* wth[3], *wtl[3];
    const int Ks[3] = {128, 256, 256};
    for (int L = 0; L < 3; L++) {
        wth[L] = (ushort*)alloc((size_t)4 * 256 * Ks[L] * 2);
        wtl[L] = (ushort*)alloc((size_t)4 * 256 * Ks[L] * 2);
    }
    ushort* wth3 = (ushort*)alloc((size_t)4 * 32 * 256 * 2);
    ushort* wtl3 = (ushort*)alloc((size_t)4 * 32 * 256 * 2);
    int*   deg     = (int*)alloc((size_t)N * 4);
    int*   pos     = (int*)alloc((size_t)N * 4);
    int*   offs    = (int*)alloc((size_t)(N + 1) * 4);
    int*   perm    = (int*)alloc((size_t)E * 4);
    int*   srcPerm = (int*)alloc((size_t)E * 4);
    int*   gofs    = (int*)alloc((GRP + 1) * 4);
    float* pooled  = (float*)alloc(GRP * HID * 4);

    // ---- CSR build (once; edge_index constant across layers) ----
    fill_i32<<<(N + 255) / 256, 256, 0, stream>>>(deg, 0, N);
    count_deg<<<(E + 255) / 256, 256, 0, stream>>>(dst, deg, E);
    scan_offsets<<<1, 256, 0, stream>>>(deg, offs, pos, N);
    scatter_edges<<<(E + 255) / 256, 256, 0, stream>>>(dst, pos, perm, E);
    gather_src<<<(E + 255) / 256, 256, 0, stream>>>(perm, src, srcPerm, E);

    // ---- W hi/lo split + transpose, once ----
    for (int L = 0; L < 3; L++) {
        W4 wp;
        for (int z = 0; z < 4; z++) wp.w[z] = W[L][z];
        dim3 gw((Ks[L] * 256 + 255) / 256, 4);
        splitT_w<<<gw, 256, 0, stream>>>(wp, wth[L], wtl[L], Ks[L], 256);
    }
    {
        W4 wp;
        for (int z = 0; z < 4; z++) wp.w[z] = W[3][z];
        dim3 gw((256 * 32 + 255) / 256, 4);
        splitT_w<<<gw, 256, 0, stream>>>(wp, wth3, wtl3, 256, 32);
    }

    const float scale = 0.17677669529663687f; // 1/sqrt(32)

    // ---- layer 0 input split (x: N x 128) ----
    split_f32<<<(int)(((long long)N * 128 + 255) / 256), 256, 0, stream>>>(
        x, ahi, alo, (long long)N * 128);

    float* skbufs[2] = {bufA, bufB};
    const int nbm = (N + 127) / 128;           // 157

    for (int L = 0; L < 3; L++) {
        const int K = Ks[L];
        float* skb = skbufs[L & 1];

        PZmfma p;
        for (int z = 0; z < 4; z++) {
            p.wh[z] = wth[L] + (size_t)z * 256 * K;
            p.wl[z] = wtl[L] + (size_t)z * 256 * K;
            p.bias[z] = B[L][z];
        }
        p.C[0] = qb; p.C[1] = nullptr; p.C[2] = nullptr; p.C[3] = skb;
        p.kv = kvh;
        const int nwg = nbm * 8;               // bm x bn(2) x z(4), %8==0
        if (K == 128) gemm4_mfma<128><<<nwg, 256, 0, stream>>>(ahi, alo, p, N);
        else          gemm4_mfma<256><<<nwg, 256, 0, stream>>>(ahi, alo, p, N);

        // dof=256 -> tpn=64 threads/node, 4 nodes/block; all emit bf16 hi/lo
        attn_fused4<true><<<(N + 3) / 4, 256, 0, stream>>>(
            (const float4*)qb, (const uint4*)kvh, (const float4*)skb,
            offs, srcPerm, nullptr, (ushort4*)ahi, (ushort4*)alo, N, 64, scale);
    }

    // ---- layer 3 (H=1, dof=32, MFMA) ----
    {
        float* skb = skbufs[1];                // bufB
        PZmfma p;
        for (int z = 0; z < 4; z++) {
            p.wh[z] = wth3 + (size_t)z * 32 * 256;
            p.wl[z] = wtl3 + (size_t)z * 32 * 256;
            p.bias[z] = B[3][z];
        }
        p.C[0] = qb; p.C[1] = nullptr; p.C[2] = nullptr; p.C[3] = skb;
        p.kv = kvh;
        const int nWork = nbm * 4;             // 628
        const int nwg   = ((nWork + 7) / 8) * 8;   // 632 (padded, %8==0)
        gemm4_mfma32<256><<<nwg, 256, 0, stream>>>(ahi, alo, p, N, nWork);

        // dof=32 -> tpn=8 threads/node, 32 nodes/block
        attn_fused4<false><<<(N + 31) / 32, 256, 0, stream>>>(
            (const float4*)qb, (const uint4*)kvh, (const float4*)skb,
            offs, srcPerm, (float4*)skb, nullptr, nullptr, N, 8, scale);

        graph_offsets<<<(N + 255) / 256, 256, 0, stream>>>(batch, gofs, N, GRP);
        pool_seg<<<GRP, 1024, 0, stream>>>(skb, gofs, pooled);
        head_kernel<<<1, 64, 0, stream>>>(pooled, wlin, blin, (float*)d_out);
    }
}